// Round 3
// baseline (6109.382 us; speedup 1.0000x reference)
//
#include <hip/hip_runtime.h>

// ============================================================================
// GRU_29300266893722  (B=64, T=512, IN=256, H=1024, OUT=256)  -- MI355X gfx950
//
// R6.2: self-validating XCD-LOCAL exchange.
// R5 (measured 3740us k_scan) pays 2 cross-XCD round trips through the IF
// coherence point per step (sc0sc1 system scope: WRITE 526MB ~ 2x exchange
// bytes, FETCH 1.29GB >> 192MB streamed inputs). Theory: chain members on ONE
// XCD can exchange through the shared per-XCD L2 with sc0-only ops (store:
// write-through L1 into L2, no IF writethrough; load: L1-bypass, L2-hit).
// R6's claim/rendezvous version was untrustworthy (XCC_ID readback unproven,
// 256-block rendezvous can deadlock under rocprof). R6.2 instead:
//   - deterministic roles: 128 blocks, chain g = {blk : blk&7==g}, g<4,
//     c=blk>>3 (dispatcher round-robins blk%8 across XCDs -> co-XCD chains);
//   - per-chain bounded TWO-PHASE sc0 PROBE (store 1, all-poll >=1; store 2,
//     all-poll >=2 -- phase 2 catches stale-L1-after-first-miss) using the
//     exact data-path access pattern; outcome reconciled via device-scope
//     atomics (ok[g]/done[g]); LOCAL iff all 16 members proved coherence;
//   - otherwise the chain runs the byte-identical measured R5 sc0sc1 path.
// Worst case = R5 + ~2ms one-time probe timeout. ctrl zeroed each launch.
// ============================================================================

#define BB 64
#define TT 512
#define KIN 256
#define HH 1024
#define NOUT 256

typedef float  f32x4 __attribute__((ext_vector_type(4)));
typedef short  s16x8 __attribute__((ext_vector_type(8)));
typedef unsigned int u32x4 __attribute__((ext_vector_type(4)));
typedef unsigned short u16x4 __attribute__((ext_vector_type(4)));

#define MFMA16(a, b, c) __builtin_amdgcn_mfma_f32_16x16x32_bf16((a), (b), (c), 0, 0, 0)

static __device__ __forceinline__ s16x8 as16(u32x4 v) { return __builtin_bit_cast(s16x8, v); }

static __device__ __forceinline__ unsigned short f2bf(float f) {
  unsigned u = __float_as_uint(f);
  u += 0x7FFFu + ((u >> 16) & 1u);   // round-to-nearest-even
  return (unsigned short)(u >> 16);
}
static __device__ __forceinline__ float bf2f(unsigned short h) {
  return __uint_as_float(((unsigned)h) << 16);
}

static __device__ __forceinline__ float tanh_fast(float x) {
  float xc = fminf(fmaxf(x, -15.f), 15.f);
  float e = __expf(2.f * xc);
  return (e - 1.f) / (e + 1.f);
}
static __device__ __forceinline__ float sigmoid_fast(float x) {
  float xc = fminf(fmaxf(x, -30.f), 30.f);
  return 1.f / (1.f + __expf(-xc));
}

// ---- exchange access helpers ----------------------------------------------
// LOCAL  = probe-proven same-XCD chain: sc0 only (per-XCD L2 exchange).
// !LOCAL = sc0 sc1 (system scope via IF) -- exact measured R5 path.
template <bool LOCAL>
static __device__ __forceinline__ void st_dw(unsigned* p, unsigned v) {
  if (LOCAL)
    asm volatile("global_store_dword %0, %1, off sc0" :: "v"(p), "v"(v) : "memory");
  else
    asm volatile("global_store_dword %0, %1, off sc0 sc1" :: "v"(p), "v"(v) : "memory");
}
template <bool LOCAL, int OFF>
static __device__ __forceinline__ void ld128o(u32x4& d, const unsigned* p) {
  if (LOCAL)
    asm volatile("global_load_dwordx4 %0, %1, off offset:%2 sc0"
                 : "=v"(d) : "v"(p), "i"(OFF));
  else
    asm volatile("global_load_dwordx4 %0, %1, off offset:%2 sc0 sc1"
                 : "=v"(d) : "v"(p), "i"(OFF));
}
// single-dword helpers for the probe/reconcile phase
static __device__ __forceinline__ void st_dw_sys(unsigned* p, unsigned v) {
  asm volatile("global_store_dword %0, %1, off sc0 sc1" :: "v"(p), "v"(v) : "memory");
}
static __device__ __forceinline__ unsigned ld_dw_sys(const unsigned* p) {
  unsigned v;
  asm volatile("global_load_dword %0, %1, off sc0 sc1\n\ts_waitcnt vmcnt(0)"
               : "=v"(v) : "v"(p) : "memory");
  return v;
}
static __device__ __forceinline__ void st_dw_sc0(unsigned* p, unsigned v) {
  asm volatile("global_store_dword %0, %1, off sc0" :: "v"(p), "v"(v) : "memory");
}
static __device__ __forceinline__ unsigned ld_dw_sc0(const unsigned* p) {
  unsigned v;
  asm volatile("global_load_dword %0, %1, off sc0\n\ts_waitcnt vmcnt(0)"
               : "=v"(v) : "v"(p) : "memory");
  return v;
}

static __device__ __forceinline__ void tie16(u32x4& a0, u32x4& a1, u32x4& a2, u32x4& a3,
                                             u32x4& a4, u32x4& a5, u32x4& a6, u32x4& a7,
                                             u32x4& a8, u32x4& a9, u32x4& aA, u32x4& aB,
                                             u32x4& aC, u32x4& aD, u32x4& aE, u32x4& aF) {
  asm volatile("s_waitcnt vmcnt(0)"
               : "+v"(a0), "+v"(a1), "+v"(a2), "+v"(a3),
                 "+v"(a4), "+v"(a5), "+v"(a6), "+v"(a7),
                 "+v"(a8), "+v"(a9), "+v"(aA), "+v"(aB),
                 "+v"(aC), "+v"(aD), "+v"(aE), "+v"(aF)
               :: "memory");
}

// pack two tagged-dword quads (cols j0..3, j4..7) into one bf16x8 frag quad
static __device__ __forceinline__ unsigned pk(unsigned hi, unsigned lo) {
  return __builtin_amdgcn_perm(hi, lo, 0x07060302u);
}
static __device__ __forceinline__ u32x4 pack_frag(u32x4 a, u32x4 b) {
  u32x4 r;
  r.x = pk(a.y, a.x); r.y = pk(a.w, a.z);
  r.z = pk(b.y, b.x); r.w = pk(b.w, b.z);
  return r;
}

// Validated A-operand load, fragment-major layout. rp0 = buf + w*4096 + lane*4
// (dwords). Retries until all tags match.
template <bool LOCAL>
static __device__ __forceinline__ void load_validated(
    const unsigned* rp0, unsigned tag, bool& dead, u32x4 (&a)[8]) {
  const unsigned* p1 = rp0 + 1024;
  const unsigned* p2 = rp0 + 2048;
  const unsigned* p3 = rp0 + 3072;
  u32x4 r0, r1, r2, r3, r4, r5, r6, r7, r8, r9, rA, rB, rC, rD, rE, rF;
  int guard = 0;
  while (true) {
    ld128o<LOCAL,0>(r0, rp0); ld128o<LOCAL,1024>(r1, rp0);
    ld128o<LOCAL,2048>(r2, rp0); ld128o<LOCAL,3072>(r3, rp0);
    ld128o<LOCAL,0>(r4, p1);  ld128o<LOCAL,1024>(r5, p1);
    ld128o<LOCAL,2048>(r6, p1);  ld128o<LOCAL,3072>(r7, p1);
    ld128o<LOCAL,0>(r8, p2);  ld128o<LOCAL,1024>(r9, p2);
    ld128o<LOCAL,2048>(rA, p2);  ld128o<LOCAL,3072>(rB, p2);
    ld128o<LOCAL,0>(rC, p3);  ld128o<LOCAL,1024>(rD, p3);
    ld128o<LOCAL,2048>(rE, p3);  ld128o<LOCAL,3072>(rF, p3);
    tie16(r0, r1, r2, r3, r4, r5, r6, r7, r8, r9, rA, rB, rC, rD, rE, rF);
    unsigned bad = 0;
#define CHK(R) bad |= (R.x ^ tag) | (R.y ^ tag) | (R.z ^ tag) | (R.w ^ tag)
    CHK(r0); CHK(r1); CHK(r2); CHK(r3); CHK(r4); CHK(r5); CHK(r6); CHK(r7);
    CHK(r8); CHK(r9); CHK(rA); CHK(rB); CHK(rC); CHK(rD); CHK(rE); CHK(rF);
#undef CHK
    bad &= 0xFFFFu;
    if (__all(bad == 0)) break;
    if (dead || ++guard > 8192) { dead = true; break; }
  }
  a[0] = pack_frag(r0, r1); a[1] = pack_frag(r2, r3);
  a[2] = pack_frag(r4, r5); a[3] = pack_frag(r6, r7);
  a[4] = pack_frag(r8, r9); a[5] = pack_frag(rA, rB);
  a[6] = pack_frag(rC, rD); a[7] = pack_frag(rE, rF);
}

// ---- workspace layout ------------------------------------------------------
static constexpr size_t SZ_XP   = (size_t)TT * BB * HH * 2;       // 64 MB
static constexpr size_t OFF_XH  = 0;
static constexpr size_t OFF_XZ  = OFF_XH + SZ_XP;
static constexpr size_t OFF_XR  = OFF_XZ + SZ_XP;
static constexpr size_t OFF_XB  = OFF_XR + SZ_XP;                 // X bf16
static constexpr size_t OFF_WHP = OFF_XB + (size_t)BB * TT * KIN * 2;
static constexpr size_t OFF_VZP = OFF_WHP + (size_t)HH * HH * 2;
static constexpr size_t OFF_VRP = OFF_VZP + (size_t)HH * HH * 2;
static constexpr size_t OFF_WXP = OFF_VRP + (size_t)HH * HH * 2;
static constexpr size_t OFF_UZP = OFF_WXP + (size_t)HH * KIN * 2;
static constexpr size_t OFF_URP = OFF_UZP + (size_t)HH * KIN * 2;
static constexpr size_t OFF_HB  = OFF_URP + (size_t)HH * KIN * 2; // 4*16*1024 tagged dwords
static constexpr size_t OFF_HRB = OFF_HB + (size_t)4 * 16 * HH * 4;
static constexpr size_t OFF_HF  = OFF_HRB + (size_t)4 * 16 * HH * 4;  // final h fp32
static constexpr size_t OFF_CTRL = OFF_HF + (size_t)BB * HH * 4;  // 256 ctrl dwords
// ctrl map: [0..63] xccbuf (4 chains x 16), [64..127] sc0-probe slots,
//           [128..131] ok[g], [132..135] done[g]

// ============================================================================
// K0: zero the probe/reconcile control words (re-poisoned between launches!)
// ============================================================================
__global__ void k_init(unsigned* __restrict__ ctrl) { ctrl[threadIdx.x] = 0u; }

// ============================================================================
// K1: X fp32 -> bf16
// ============================================================================
__global__ void __launch_bounds__(256) k_convert_x(const float* __restrict__ X,
                                                   unsigned short* __restrict__ Xb) {
  size_t i = ((size_t)blockIdx.x * 256 + threadIdx.x) * 4;
  f32x4 v = *(const f32x4*)(X + i);
  u16x4 o = { f2bf(v[0]), f2bf(v[1]), f2bf(v[2]), f2bf(v[3]) };
  *(u16x4*)(Xb + i) = o;
}

// ============================================================================
// K2: pack weights W[1024][K] fp32 -> bf16 MFMA B-fragment layout
// ============================================================================
__global__ void __launch_bounds__(256) k_pack_w(
    const float* __restrict__ Wh, const float* __restrict__ Vz, const float* __restrict__ Vr,
    const float* __restrict__ Wx, const float* __restrict__ Uz, const float* __restrict__ Ur,
    unsigned short* __restrict__ Whp, unsigned short* __restrict__ Vzp, unsigned short* __restrict__ Vrp,
    unsigned short* __restrict__ Wxp, unsigned short* __restrict__ Uzp, unsigned short* __restrict__ Urp) {
  int z = blockIdx.y;
  const float* src; unsigned short* dst; int K;
  switch (z) {
    case 0: src = Wh; dst = Whp; K = 1024; break;
    case 1: src = Vz; dst = Vzp; K = 1024; break;
    case 2: src = Vr; dst = Vrp; K = 1024; break;
    case 3: src = Wx; dst = Wxp; K = 256;  break;
    case 4: src = Uz; dst = Uzp; K = 256;  break;
    default: src = Ur; dst = Urp; K = 256; break;
  }
  int KK = K >> 5;
  int total = 64 * KK * 64;
  int tau = blockIdx.x * 256 + threadIdx.x;
  if (tau >= total) return;
  int lane = tau & 63;
  int kk = (tau >> 6) % KK;
  int ct = tau / (KK * 64);
  int q = lane >> 4, cl = lane & 15;
  const float* s = src + (size_t)(ct * 16 + cl) * K + kk * 32 + q * 8;
  f32x4 v0 = *(const f32x4*)s;
  f32x4 v1 = *(const f32x4*)(s + 4);
  u32x4 o;
  o.x = (unsigned)f2bf(v0[0]) | ((unsigned)f2bf(v0[1]) << 16);
  o.y = (unsigned)f2bf(v0[2]) | ((unsigned)f2bf(v0[3]) << 16);
  o.z = (unsigned)f2bf(v1[0]) | ((unsigned)f2bf(v1[1]) << 16);
  o.w = (unsigned)f2bf(v1[2]) | ((unsigned)f2bf(v1[3]) << 16);
  *(u32x4*)(dst + (size_t)tau * 8) = o;
}

// ============================================================================
// K3: XH/XZ/XR[t][b][h] (bf16) = X @ {Wx,Uz,Ur}^T + bias.  grid (512,16,3).
// ============================================================================
__global__ void __launch_bounds__(256) k_proj(
    const unsigned short* __restrict__ Xb,
    const unsigned short* __restrict__ Wxp, const unsigned short* __restrict__ Uzp,
    const unsigned short* __restrict__ Urp,
    const float* __restrict__ bx, const float* __restrict__ bz, const float* __restrict__ br,
    unsigned short* __restrict__ XH, unsigned short* __restrict__ XZ, unsigned short* __restrict__ XR) {
  __shared__ u32x4 As[4 * 8 * 64];  // 32 KB
  const int tid = threadIdx.x;
  const int mb = blockIdx.x, cb = blockIdx.y, mu = blockIdx.z;

#pragma unroll
  for (int i = 0; i < 8; ++i) {
    int fid = i * 256 + tid;
    int lane = fid & 63, kk = (fid >> 6) & 7, rt = fid >> 9;
    int q = lane >> 4, cl = lane & 15;
    int mrow = mb * 64 + rt * 16 + cl;
    As[fid] = *(const u32x4*)(Xb + (size_t)mrow * KIN + kk * 32 + q * 8);
  }
  __syncthreads();

  const int lane = tid & 63, w = tid >> 6;
  const int q = lane >> 4, cl = lane & 15;
  const unsigned short* Bp = (mu == 0) ? Wxp : (mu == 1) ? Uzp : Urp;
  const float* bias        = (mu == 0) ? bx  : (mu == 1) ? bz  : br;
  unsigned short* Dst      = (mu == 0) ? XH  : (mu == 1) ? XZ  : XR;

  f32x4 z4 = {0.f, 0.f, 0.f, 0.f};
  f32x4 acc[4] = {z4, z4, z4, z4};
  const int ctg = cb * 4 + w;
#pragma unroll
  for (int kk = 0; kk < 8; ++kk) {
    u32x4 b = *(const u32x4*)(Bp + ((size_t)(ctg * 8 + kk) * 64 + lane) * 8);
#pragma unroll
    for (int rt = 0; rt < 4; ++rt)
      acc[rt] = MFMA16(as16(As[(rt * 8 + kk) * 64 + lane]), as16(b), acc[rt]);
  }
  const int col = cb * 64 + w * 16 + cl;
  const float bv = bias[col];
#pragma unroll
  for (int rt = 0; rt < 4; ++rt) {
#pragma unroll
    for (int j = 0; j < 4; ++j) {
      int m = mb * 64 + rt * 16 + q * 4 + j;   // m = b*512 + t
      int t = m & (TT - 1), b = m >> 9;
      Dst[((size_t)t * BB + b) * HH + col] = f2bf(acc[rt][j] + bv);
    }
  }
}

// ============================================================================
// K4 body: persistent scan for one chain-role (g, c), protocol LOCAL/GLOBAL.
//   wave w: K-slice [256w,256w+256), owns cols c*64+w*16+cl, rows q*4+j.
// ============================================================================
template <bool LOCAL>
static __device__ __forceinline__ void scan_loop(
    const int tid, const int g, const int c,
    const unsigned short* __restrict__ XH, const unsigned short* __restrict__ XZ,
    const unsigned short* __restrict__ XR,
    const unsigned short* __restrict__ Whp, const unsigned short* __restrict__ Vzp,
    const unsigned short* __restrict__ Vrp,
    unsigned* __restrict__ hb32all, unsigned* __restrict__ hrb32all,
    float* __restrict__ hfinal,
    f32x4* redA, f32x4* redB, f32x4* redC) {
  const int lane = tid & 63, w = tid >> 6;
  const int q = lane >> 4, cl = lane & 15;
  const int c4 = c * 4, kw = w * 8;

  unsigned* hb  = hb32all  + (size_t)g * 16 * HH;
  unsigned* hrb = hrb32all + (size_t)g * 16 * HH;

  // resident weight fragments: Wh + Vz (256 VGPRs); Vr streamed per step
  u32x4 wh[4][8], vz[4][8];
#pragma unroll
  for (int ct = 0; ct < 4; ++ct)
#pragma unroll
    for (int k = 0; k < 8; ++k) {
      size_t fi = (((size_t)(c4 + ct) * 32 + kw + k) * 64 + lane) * 8;
      wh[ct][k] = *(const u32x4*)(Whp + fi);
      vz[ct][k] = *(const u32x4*)(Vzp + fi);
    }

  const int hcol = c * 64 + w * 16 + cl;         // owned output column
  const int brow0 = g * 16 + q * 4;              // owned batch rows (+j)

  // consumer read bases (fragment-major): buf + w*4096 + lane*4 dwords
  const unsigned* rpA = hrb + w * 4096 + lane * 4;
  const unsigned* rpB = hb  + w * 4096 + lane * 4;
  // producer store bases: dword idx = (wd*8+kd)*512 + half*256 + laned*4 + jm
  const unsigned C = (unsigned)hcol;
  const unsigned sbase = ((C >> 8) * 8 + ((C >> 5) & 7)) * 512 + ((C >> 2) & 1) * 256 +
                         (((C >> 3) & 3) * 16 + q * 4) * 4 + (C & 3);
  unsigned* spA = hb  + sbase;    // row j store at + j*4
  unsigned* spB = hrb + sbase;

  const f32x4 z4 = {0.f, 0.f, 0.f, 0.f};
  f32x4 hreg = z4, zreg = z4;
  bool dead = false;

  for (int t = 0; t < TT; ++t) {
    // ---------------- phase A: h update ----------------
    unsigned short xh_u[4];
#pragma unroll
    for (int j = 0; j < 4; ++j)
      xh_u[j] = XH[((size_t)t * BB + brow0 + j) * HH + hcol];

    f32x4 acc[4] = {z4, z4, z4, z4};
    if (t > 0) {
      u32x4 a[8];
      load_validated<LOCAL>(rpA, (unsigned)t, dead, a);
#pragma unroll
      for (int k = 0; k < 8; ++k) {
        s16x8 av = as16(a[k]);
#pragma unroll
        for (int ct = 0; ct < 4; ++ct)
          acc[ct] = MFMA16(av, as16(wh[ct][k]), acc[ct]);
      }
    }
#pragma unroll
    for (int ct = 0; ct < 4; ++ct) redA[(w * 4 + ct) * 64 + lane] = acc[ct];
    __syncthreads();
    f32x4 S = redA[(0 * 4 + w) * 64 + lane];
    S += redA[(1 * 4 + w) * 64 + lane];
    S += redA[(2 * 4 + w) * 64 + lane];
    S += redA[(3 * 4 + w) * 64 + lane];

    const unsigned tagn = (unsigned)(t + 1);
    if (t == TT - 1) {
#pragma unroll
      for (int j = 0; j < 4; ++j) {
        float pre = S[j] + bf2f(xh_u[j]);
        float ht = tanh_fast(pre);
        hreg[j] = zreg[j] * hreg[j] + (1.f - zreg[j]) * ht;
      }
      break;
    }
#pragma unroll
    for (int j = 0; j < 4; ++j) {
      float pre = S[j] + bf2f(xh_u[j]);
      float ht = tanh_fast(pre);
      float hn = zreg[j] * hreg[j] + (1.f - zreg[j]) * ht;
      hreg[j] = hn;
      st_dw<LOCAL>(spA + j * 4, ((unsigned)f2bf(hn) << 16) | tagn);
    }

    // ---------------- phase B: gates ----------------
    unsigned short xz_u[4], xr_u[4];
#pragma unroll
    for (int j = 0; j < 4; ++j) {
      xz_u[j] = XZ[((size_t)t * BB + brow0 + j) * HH + hcol];
      xr_u[j] = XR[((size_t)t * BB + brow0 + j) * HH + hcol];
    }
    u32x4 b[8];
    load_validated<LOCAL>(rpB, tagn, dead, b);

    f32x4 az[4] = {z4, z4, z4, z4};
    f32x4 ar[4] = {z4, z4, z4, z4};
#pragma unroll
    for (int ct = 0; ct < 4; ++ct) {
      u32x4 vrk[8];
#pragma unroll
      for (int k = 0; k < 8; ++k)
        vrk[k] = *(const u32x4*)(Vrp + (((size_t)(c4 + ct) * 32 + kw + k) * 64 + lane) * 8);
#pragma unroll
      for (int k = 0; k < 8; ++k)
        az[ct] = MFMA16(as16(b[k]), as16(vz[ct][k]), az[ct]);
#pragma unroll
      for (int k = 0; k < 8; ++k)
        ar[ct] = MFMA16(as16(b[k]), as16(vrk[k]), ar[ct]);
    }
#pragma unroll
    for (int ct = 0; ct < 4; ++ct) {
      redB[(w * 4 + ct) * 64 + lane] = az[ct];
      redC[(w * 4 + ct) * 64 + lane] = ar[ct];
    }
    __syncthreads();
    f32x4 Sz = redB[(0 * 4 + w) * 64 + lane];
    Sz += redB[(1 * 4 + w) * 64 + lane];
    Sz += redB[(2 * 4 + w) * 64 + lane];
    Sz += redB[(3 * 4 + w) * 64 + lane];
    f32x4 Sr = redC[(0 * 4 + w) * 64 + lane];
    Sr += redC[(1 * 4 + w) * 64 + lane];
    Sr += redC[(2 * 4 + w) * 64 + lane];
    Sr += redC[(3 * 4 + w) * 64 + lane];

#pragma unroll
    for (int j = 0; j < 4; ++j) {
      float zv = sigmoid_fast(Sz[j] + bf2f(xz_u[j]));
      float rv = sigmoid_fast(Sr[j] + bf2f(xr_u[j]));
      zreg[j] = zv;
      st_dw<LOCAL>(spB + j * 4, ((unsigned)f2bf(rv * hreg[j]) << 16) | tagn);
    }
  }

  // epilogue: final h fp32 (plain stores; visible at kernel boundary)
#pragma unroll
  for (int j = 0; j < 4; ++j)
    hfinal[(size_t)(brow0 + j) * HH + hcol] = hreg[j];
}

// ============================================================================
// K4: 128 blocks. chain g = blocks {blk&7 == g}, g<4; slot c = blk>>3.
// Per-chain probe proves (or refutes) sc0 intra-XCD coherence; LOCAL iff all
// 16 members passed, else byte-identical R5 GLOBAL protocol. Residues 4..7
// exit immediately.
// ============================================================================
__global__ void __launch_bounds__(256, 1) k_scan(
    const unsigned short* __restrict__ XH, const unsigned short* __restrict__ XZ,
    const unsigned short* __restrict__ XR,
    const unsigned short* __restrict__ Whp, const unsigned short* __restrict__ Vzp,
    const unsigned short* __restrict__ Vrp,
    unsigned* __restrict__ hb32all, unsigned* __restrict__ hrb32all,
    float* __restrict__ hfinal, unsigned* __restrict__ ctrl) {
  __shared__ f32x4 redA[16 * 64];  // 16 KB
  __shared__ f32x4 redB[16 * 64];  // 16 KB
  __shared__ f32x4 redC[16 * 64];  // 16 KB
  __shared__ int shp[4];

  const int blk = blockIdx.x;
  const int g = blk & 7, c = blk >> 3;
  if (g >= 4) return;              // unused residue -> exit
  const int tid = threadIdx.x;

  if (tid == 0) {
    unsigned* xcb = ctrl;             // [0..63]
    unsigned* prb = ctrl + 64;        // [64..127]
    unsigned* okc = ctrl + 128;       // [128..131]
    unsigned* dnc = ctrl + 132;       // [132..135]

    unsigned xcc;
    asm volatile("s_getreg_b32 %0, hwreg(HW_REG_XCC_ID)" : "=s"(xcc));
    xcc &= 15u;
    // publish own XCC id (system scope, reliable)
    st_dw_sys(&xcb[g * 16 + c], 0x100u | xcc);
    // gather all 16 members' ids (bounded; all members are resident)
    unsigned vals[16];
    bool got = true;
    for (int i = 0; i < 16; ++i) {
      unsigned v = 0; int gd = 0;
      do {
        v = ld_dw_sys(&xcb[g * 16 + i]);
        if (++gd > (1 << 20)) { got = false; break; }
        if (!(v & 0x100u)) __builtin_amdgcn_s_sleep(2);
      } while (!(v & 0x100u));
      vals[i] = v & 0xFFu;
      if (!got) break;
    }
    bool same = got;
    if (got)
      for (int i = 1; i < 16; ++i) same = same && (vals[i] == vals[0]);

    // two-phase sc0 probe: phase 2 (observe 1 -> 2 transition) detects
    // "first load missed L1, later loads stale" -- the data-path pattern.
    unsigned s = 0;
    if (same) {
      st_dw_sc0(&prb[g * 16 + c], 1u);
      bool ok1 = true;
      for (int i = 0; i < 16 && ok1; ++i) {
        int gd = 0;
        while (ld_dw_sc0(&prb[g * 16 + i]) < 1u) {
          if (++gd > (1 << 14)) { ok1 = false; break; }
        }
      }
      if (ok1) {
        st_dw_sc0(&prb[g * 16 + c], 2u);
        bool ok2 = true;
        for (int i = 0; i < 16 && ok2; ++i) {
          int gd = 0;
          while (ld_dw_sc0(&prb[g * 16 + i]) < 2u) {
            if (++gd > (1 << 14)) { ok2 = false; break; }
          }
        }
        s = ok2 ? 1u : 0u;
      }
    }
    // reconcile: unanimous per-chain decision via device-scope atomics
    atomicAdd(&okc[g], s);
    atomicAdd(&dnc[g], 1u);
    while (atomicAdd(&dnc[g], 0u) < 16u) __builtin_amdgcn_s_sleep(4);
    unsigned okv = atomicAdd(&okc[g], 0u);
    shp[0] = (okv == 16u) ? 1 : 0;
  }
  __syncthreads();
  const int loc = shp[0];

  if (loc)
    scan_loop<true>(tid, g, c, XH, XZ, XR, Whp, Vzp, Vrp,
                    hb32all, hrb32all, hfinal, redA, redB, redC);
  else
    scan_loop<false>(tid, g, c, XH, XZ, XR, Whp, Vzp, Vrp,
                     hb32all, hrb32all, hfinal, redA, redB, redC);
}

// ============================================================================
// K5: out[b][o] = dot(h[b,:], Wo[o,:]) + bo[o]   (fp32)
// ============================================================================
__global__ void __launch_bounds__(256) k_out(const float* __restrict__ hf,
                                             const float* __restrict__ Wo,
                                             const float* __restrict__ bo,
                                             float* __restrict__ out) {
  __shared__ float hs[HH];
  const int b = blockIdx.x, tid = threadIdx.x;
  *(f32x4*)&hs[tid * 4] = *(const f32x4*)(hf + (size_t)b * HH + tid * 4);
  __syncthreads();
  float acc = bo[tid];
  const f32x4* wr = (const f32x4*)(Wo + (size_t)tid * HH);
#pragma unroll 8
  for (int k = 0; k < HH / 4; ++k) {
    f32x4 wv = wr[k];
    f32x4 hv = *(const f32x4*)&hs[k * 4];
    acc += wv[0] * hv[0] + wv[1] * hv[1] + wv[2] * hv[2] + wv[3] * hv[3];
  }
  out[(size_t)b * NOUT + tid] = acc;
}

// ============================================================================
extern "C" void kernel_launch(void* const* d_in, const int* in_sizes, int n_in,
                              void* d_out, int out_size, void* d_ws, size_t ws_size,
                              hipStream_t stream) {
  (void)in_sizes; (void)n_in; (void)out_size; (void)ws_size;
  const float* X  = (const float*)d_in[0];
  const float* Wx = (const float*)d_in[1];
  const float* bx = (const float*)d_in[2];
  const float* Wh = (const float*)d_in[3];
  const float* Uz = (const float*)d_in[4];
  const float* bz = (const float*)d_in[5];
  const float* Vz = (const float*)d_in[6];
  const float* Ur = (const float*)d_in[7];
  const float* br = (const float*)d_in[8];
  const float* Vr = (const float*)d_in[9];
  const float* Wo = (const float*)d_in[10];
  const float* bo = (const float*)d_in[11];

  char* ws = (char*)d_ws;
  unsigned short* XHp = (unsigned short*)(ws + OFF_XH);
  unsigned short* XZp = (unsigned short*)(ws + OFF_XZ);
  unsigned short* XRp = (unsigned short*)(ws + OFF_XR);
  unsigned short* Xb  = (unsigned short*)(ws + OFF_XB);
  unsigned short* Whp = (unsigned short*)(ws + OFF_WHP);
  unsigned short* Vzp = (unsigned short*)(ws + OFF_VZP);
  unsigned short* Vrp = (unsigned short*)(ws + OFF_VRP);
  unsigned short* Wxp = (unsigned short*)(ws + OFF_WXP);
  unsigned short* Uzp = (unsigned short*)(ws + OFF_UZP);
  unsigned short* Urp = (unsigned short*)(ws + OFF_URP);
  unsigned* hbp  = (unsigned*)(ws + OFF_HB);
  unsigned* hrbp = (unsigned*)(ws + OFF_HRB);
  float* hfp = (float*)(ws + OFF_HF);
  unsigned* ctrl = (unsigned*)(ws + OFF_CTRL);

  k_init<<<1, 256, 0, stream>>>(ctrl);
  k_convert_x<<<8192, 256, 0, stream>>>(X, Xb);
  k_pack_w<<<dim3(512, 6), 256, 0, stream>>>(Wh, Vz, Vr, Wx, Uz, Ur,
                                             Whp, Vzp, Vrp, Wxp, Uzp, Urp);
  k_proj<<<dim3(512, 16, 3), 256, 0, stream>>>(Xb, Wxp, Uzp, Urp, bx, bz, br,
                                               XHp, XZp, XRp);
  k_scan<<<128, 256, 0, stream>>>(XHp, XZp, XRp, Whp, Vzp, Vrp,
                                  hbp, hrbp, hfp, ctrl);
  k_out<<<64, 256, 0, stream>>>(hfp, Wo, bo, (float*)d_out);
}

// Round 4
// 4035.115 us; speedup vs baseline: 1.5141x; 1.5141x over previous
//
#include <hip/hip_runtime.h>

// ============================================================================
// GRU_29300266893722  (B=64, T=512, IN=256, H=1024, OUT=256)  -- MI355X gfx950
//
// R7 = exact revert to R5 (best measured: 3994us total, k_scan 3740us).
// R3 protocol: tag-in-data, fire-and-forget sc0sc1 stores, validated loads,
// exchange buffers in CONSUMER FRAGMENT-MAJOR layout:
//   dword index (w,k,half,lane,jm) = (w*8+k)*512 + half*256 + lane*4 + jm
//   holds tagged h[row=lane&15][col = 256w + 32k + 8*(lane>>4) + half*4+jm]
// -> each consumer ld128 is contiguous (1KB span, 16 lines).
//
// Exchange-protocol design space now measured:
//   R4  sentinel/atomic gating          -> +1.8ms (atomics don't change
//       residency; extra gate RT + retry rounds hurt)
//   R6  co-XCD chains + plain ld/buffer_inv -> WRONG (stale L1 spin)
//   R6.2 co-XCD chains + sc0-only       -> CORRECT but +57% (FETCH drops
//       1.29GB->337MB proving L2-served polls, yet WRITE unchanged 526MB:
//       sc0 stores still drain to memory side; store-visibility lag +
//       single-XCD L2 port contention dominate. Load-side latency was NOT
//       the bottleneck; store-side visibility is.)
//   R5  sc0sc1 + scattered blocks       -> 3740us  <- THIS KERNEL
// Remaining ideas all fail arithmetic checks (wide stores -> 4x consumer
// packets; redundant-r -> 512KB/wave/step Vr stream; full-K-per-wave ->
// 4x poll volume). This structure is the empirical optimum of the family.
// ============================================================================

#define BB 64
#define TT 512
#define KIN 256
#define HH 1024
#define NOUT 256

typedef float  f32x4 __attribute__((ext_vector_type(4)));
typedef short  s16x8 __attribute__((ext_vector_type(8)));
typedef unsigned int u32x4 __attribute__((ext_vector_type(4)));
typedef unsigned short u16x4 __attribute__((ext_vector_type(4)));

#define MFMA16(a, b, c) __builtin_amdgcn_mfma_f32_16x16x32_bf16((a), (b), (c), 0, 0, 0)

static __device__ __forceinline__ s16x8 as16(u32x4 v) { return __builtin_bit_cast(s16x8, v); }

static __device__ __forceinline__ unsigned short f2bf(float f) {
  unsigned u = __float_as_uint(f);
  u += 0x7FFFu + ((u >> 16) & 1u);   // round-to-nearest-even
  return (unsigned short)(u >> 16);
}
static __device__ __forceinline__ float bf2f(unsigned short h) {
  return __uint_as_float(((unsigned)h) << 16);
}

static __device__ __forceinline__ float tanh_fast(float x) {
  float xc = fminf(fmaxf(x, -15.f), 15.f);
  float e = __expf(2.f * xc);
  return (e - 1.f) / (e + 1.f);
}
static __device__ __forceinline__ float sigmoid_fast(float x) {
  float xc = fminf(fmaxf(x, -30.f), 30.f);
  return 1.f / (1.f + __expf(-xc));
}

// ---- device-scope (IF-coherent) access helpers -----------------------------
static __device__ __forceinline__ void st_dw(unsigned* p, unsigned v) {
  asm volatile("global_store_dword %0, %1, off sc0 sc1" :: "v"(p), "v"(v) : "memory");
}
template <int OFF>
static __device__ __forceinline__ void ld128o(u32x4& d, const unsigned* p) {
  asm volatile("global_load_dwordx4 %0, %1, off offset:%2 sc0 sc1"
               : "=v"(d) : "v"(p), "i"(OFF));
}
static __device__ __forceinline__ void tie16(u32x4& a0, u32x4& a1, u32x4& a2, u32x4& a3,
                                             u32x4& a4, u32x4& a5, u32x4& a6, u32x4& a7,
                                             u32x4& a8, u32x4& a9, u32x4& aA, u32x4& aB,
                                             u32x4& aC, u32x4& aD, u32x4& aE, u32x4& aF) {
  asm volatile("s_waitcnt vmcnt(0)"
               : "+v"(a0), "+v"(a1), "+v"(a2), "+v"(a3),
                 "+v"(a4), "+v"(a5), "+v"(a6), "+v"(a7),
                 "+v"(a8), "+v"(a9), "+v"(aA), "+v"(aB),
                 "+v"(aC), "+v"(aD), "+v"(aE), "+v"(aF)
               :: "memory");
}

// pack two tagged-dword quads (cols j0..3, j4..7) into one bf16x8 frag quad
static __device__ __forceinline__ unsigned pk(unsigned hi, unsigned lo) {
  return __builtin_amdgcn_perm(hi, lo, 0x07060302u);
}
static __device__ __forceinline__ u32x4 pack_frag(u32x4 a, u32x4 b) {
  u32x4 r;
  r.x = pk(a.y, a.x); r.y = pk(a.w, a.z);
  r.z = pk(b.y, b.x); r.w = pk(b.w, b.z);
  return r;
}

// Validated A-operand load, fragment-major layout. rp0 = buf + w*4096 + lane*4
// (dwords). Frag k: lo at k*2048B, hi at +1024B; 4 base pointers keep the
// 13-bit signed immediate offsets in range. Retries until all tags match.
static __device__ __forceinline__ void load_validated(
    const unsigned* rp0, unsigned tag, bool& dead, u32x4 (&a)[8]) {
  const unsigned* p1 = rp0 + 1024;
  const unsigned* p2 = rp0 + 2048;
  const unsigned* p3 = rp0 + 3072;
  u32x4 r0, r1, r2, r3, r4, r5, r6, r7, r8, r9, rA, rB, rC, rD, rE, rF;
  int guard = 0;
  while (true) {
    ld128o<0>(r0, rp0); ld128o<1024>(r1, rp0); ld128o<2048>(r2, rp0); ld128o<3072>(r3, rp0);
    ld128o<0>(r4, p1);  ld128o<1024>(r5, p1);  ld128o<2048>(r6, p1);  ld128o<3072>(r7, p1);
    ld128o<0>(r8, p2);  ld128o<1024>(r9, p2);  ld128o<2048>(rA, p2);  ld128o<3072>(rB, p2);
    ld128o<0>(rC, p3);  ld128o<1024>(rD, p3);  ld128o<2048>(rE, p3);  ld128o<3072>(rF, p3);
    tie16(r0, r1, r2, r3, r4, r5, r6, r7, r8, r9, rA, rB, rC, rD, rE, rF);
    unsigned bad = 0;
#define CHK(R) bad |= (R.x ^ tag) | (R.y ^ tag) | (R.z ^ tag) | (R.w ^ tag)
    CHK(r0); CHK(r1); CHK(r2); CHK(r3); CHK(r4); CHK(r5); CHK(r6); CHK(r7);
    CHK(r8); CHK(r9); CHK(rA); CHK(rB); CHK(rC); CHK(rD); CHK(rE); CHK(rF);
#undef CHK
    bad &= 0xFFFFu;
    if (__all(bad == 0)) break;
    if (dead || ++guard > 4096) { dead = true; break; }
  }
  a[0] = pack_frag(r0, r1); a[1] = pack_frag(r2, r3);
  a[2] = pack_frag(r4, r5); a[3] = pack_frag(r6, r7);
  a[4] = pack_frag(r8, r9); a[5] = pack_frag(rA, rB);
  a[6] = pack_frag(rC, rD); a[7] = pack_frag(rE, rF);
}

// ---- workspace layout ------------------------------------------------------
static constexpr size_t SZ_XP   = (size_t)TT * BB * HH * 2;       // 64 MB
static constexpr size_t OFF_XH  = 0;
static constexpr size_t OFF_XZ  = OFF_XH + SZ_XP;
static constexpr size_t OFF_XR  = OFF_XZ + SZ_XP;
static constexpr size_t OFF_XB  = OFF_XR + SZ_XP;                 // X bf16
static constexpr size_t OFF_WHP = OFF_XB + (size_t)BB * TT * KIN * 2;
static constexpr size_t OFF_VZP = OFF_WHP + (size_t)HH * HH * 2;
static constexpr size_t OFF_VRP = OFF_VZP + (size_t)HH * HH * 2;
static constexpr size_t OFF_WXP = OFF_VRP + (size_t)HH * HH * 2;
static constexpr size_t OFF_UZP = OFF_WXP + (size_t)HH * KIN * 2;
static constexpr size_t OFF_URP = OFF_UZP + (size_t)HH * KIN * 2;
static constexpr size_t OFF_HB  = OFF_URP + (size_t)HH * KIN * 2; // 4*16*1024 tagged dwords
static constexpr size_t OFF_HRB = OFF_HB + (size_t)4 * 16 * HH * 4;
static constexpr size_t OFF_HF  = OFF_HRB + (size_t)4 * 16 * HH * 4;  // final h fp32

// ============================================================================
// K1: X fp32 -> bf16
// ============================================================================
__global__ void __launch_bounds__(256) k_convert_x(const float* __restrict__ X,
                                                   unsigned short* __restrict__ Xb) {
  size_t i = ((size_t)blockIdx.x * 256 + threadIdx.x) * 4;
  f32x4 v = *(const f32x4*)(X + i);
  u16x4 o = { f2bf(v[0]), f2bf(v[1]), f2bf(v[2]), f2bf(v[3]) };
  *(u16x4*)(Xb + i) = o;
}

// ============================================================================
// K2: pack weights W[1024][K] fp32 -> bf16 MFMA B-fragment layout
// ============================================================================
__global__ void __launch_bounds__(256) k_pack_w(
    const float* __restrict__ Wh, const float* __restrict__ Vz, const float* __restrict__ Vr,
    const float* __restrict__ Wx, const float* __restrict__ Uz, const float* __restrict__ Ur,
    unsigned short* __restrict__ Whp, unsigned short* __restrict__ Vzp, unsigned short* __restrict__ Vrp,
    unsigned short* __restrict__ Wxp, unsigned short* __restrict__ Uzp, unsigned short* __restrict__ Urp) {
  int z = blockIdx.y;
  const float* src; unsigned short* dst; int K;
  switch (z) {
    case 0: src = Wh; dst = Whp; K = 1024; break;
    case 1: src = Vz; dst = Vzp; K = 1024; break;
    case 2: src = Vr; dst = Vrp; K = 1024; break;
    case 3: src = Wx; dst = Wxp; K = 256;  break;
    case 4: src = Uz; dst = Uzp; K = 256;  break;
    default: src = Ur; dst = Urp; K = 256; break;
  }
  int KK = K >> 5;
  int total = 64 * KK * 64;
  int tau = blockIdx.x * 256 + threadIdx.x;
  if (tau >= total) return;
  int lane = tau & 63;
  int kk = (tau >> 6) % KK;
  int ct = tau / (KK * 64);
  int q = lane >> 4, cl = lane & 15;
  const float* s = src + (size_t)(ct * 16 + cl) * K + kk * 32 + q * 8;
  f32x4 v0 = *(const f32x4*)s;
  f32x4 v1 = *(const f32x4*)(s + 4);
  u32x4 o;
  o.x = (unsigned)f2bf(v0[0]) | ((unsigned)f2bf(v0[1]) << 16);
  o.y = (unsigned)f2bf(v0[2]) | ((unsigned)f2bf(v0[3]) << 16);
  o.z = (unsigned)f2bf(v1[0]) | ((unsigned)f2bf(v1[1]) << 16);
  o.w = (unsigned)f2bf(v1[2]) | ((unsigned)f2bf(v1[3]) << 16);
  *(u32x4*)(dst + (size_t)tau * 8) = o;
}

// ============================================================================
// K3: XH/XZ/XR[t][b][h] (bf16) = X @ {Wx,Uz,Ur}^T + bias.  grid (512,16,3).
// ============================================================================
__global__ void __launch_bounds__(256) k_proj(
    const unsigned short* __restrict__ Xb,
    const unsigned short* __restrict__ Wxp, const unsigned short* __restrict__ Uzp,
    const unsigned short* __restrict__ Urp,
    const float* __restrict__ bx, const float* __restrict__ bz, const float* __restrict__ br,
    unsigned short* __restrict__ XH, unsigned short* __restrict__ XZ, unsigned short* __restrict__ XR) {
  __shared__ u32x4 As[4 * 8 * 64];  // 32 KB
  const int tid = threadIdx.x;
  const int mb = blockIdx.x, cb = blockIdx.y, mu = blockIdx.z;

#pragma unroll
  for (int i = 0; i < 8; ++i) {
    int fid = i * 256 + tid;
    int lane = fid & 63, kk = (fid >> 6) & 7, rt = fid >> 9;
    int q = lane >> 4, cl = lane & 15;
    int mrow = mb * 64 + rt * 16 + cl;
    As[fid] = *(const u32x4*)(Xb + (size_t)mrow * KIN + kk * 32 + q * 8);
  }
  __syncthreads();

  const int lane = tid & 63, w = tid >> 6;
  const int q = lane >> 4, cl = lane & 15;
  const unsigned short* Bp = (mu == 0) ? Wxp : (mu == 1) ? Uzp : Urp;
  const float* bias        = (mu == 0) ? bx  : (mu == 1) ? bz  : br;
  unsigned short* Dst      = (mu == 0) ? XH  : (mu == 1) ? XZ  : XR;

  f32x4 z4 = {0.f, 0.f, 0.f, 0.f};
  f32x4 acc[4] = {z4, z4, z4, z4};
  const int ctg = cb * 4 + w;
#pragma unroll
  for (int kk = 0; kk < 8; ++kk) {
    u32x4 b = *(const u32x4*)(Bp + ((size_t)(ctg * 8 + kk) * 64 + lane) * 8);
#pragma unroll
    for (int rt = 0; rt < 4; ++rt)
      acc[rt] = MFMA16(as16(As[(rt * 8 + kk) * 64 + lane]), as16(b), acc[rt]);
  }
  const int col = cb * 64 + w * 16 + cl;
  const float bv = bias[col];
#pragma unroll
  for (int rt = 0; rt < 4; ++rt) {
#pragma unroll
    for (int j = 0; j < 4; ++j) {
      int m = mb * 64 + rt * 16 + q * 4 + j;   // m = b*512 + t
      int t = m & (TT - 1), b = m >> 9;
      Dst[((size_t)t * BB + b) * HH + col] = f2bf(acc[rt][j] + bv);
    }
  }
}

// ============================================================================
// K4: persistent scan, tag-in-data, fragment-major exchange buffers.
//   64 blocks x 256 threads. chain g = blk>>4 (rows 16g..16g+15),
//   col-block c = blk&15 (cols 64c..64c+63). wave w: K-slice [256w,256w+256),
//   owns state for cols c*64+w*16+cl, rows q*4+j (C/D layout).
// ============================================================================
__global__ void __launch_bounds__(256, 1) k_scan(
    const unsigned short* __restrict__ XH, const unsigned short* __restrict__ XZ,
    const unsigned short* __restrict__ XR,
    const unsigned short* __restrict__ Whp, const unsigned short* __restrict__ Vzp,
    const unsigned short* __restrict__ Vrp,
    unsigned* __restrict__ hb32all, unsigned* __restrict__ hrb32all,
    float* __restrict__ hfinal) {
  __shared__ f32x4 redA[16 * 64];  // 16 KB
  __shared__ f32x4 redB[16 * 64];  // 16 KB
  __shared__ f32x4 redC[16 * 64];  // 16 KB

  const int tid = threadIdx.x;
  const int lane = tid & 63, w = tid >> 6;
  const int q = lane >> 4, cl = lane & 15;
  const int blk = blockIdx.x;
  const int g = blk >> 4, c = blk & 15;   // chain, col-block
  const int c4 = c * 4, kw = w * 8;

  unsigned* hb  = hb32all  + (size_t)g * 16 * HH;
  unsigned* hrb = hrb32all + (size_t)g * 16 * HH;

  // resident weight fragments: Wh + Vz (256 VGPRs); Vr streamed per step
  u32x4 wh[4][8], vz[4][8];
#pragma unroll
  for (int ct = 0; ct < 4; ++ct)
#pragma unroll
    for (int k = 0; k < 8; ++k) {
      size_t fi = (((size_t)(c4 + ct) * 32 + kw + k) * 64 + lane) * 8;
      wh[ct][k] = *(const u32x4*)(Whp + fi);
      vz[ct][k] = *(const u32x4*)(Vzp + fi);
    }

  const int hcol = c * 64 + w * 16 + cl;         // owned output column
  const int brow0 = g * 16 + q * 4;              // owned batch rows (+j)

  // consumer read bases (fragment-major): buf + w*4096 + lane*4 dwords
  const unsigned* rpA = hrb + w * 4096 + lane * 4;
  const unsigned* rpB = hb  + w * 4096 + lane * 4;
  // producer store bases: dword idx = (wd*8+kd)*512 + half*256 + laned*4 + jm
  //   wd=C>>8, kd=(C>>5)&7, half=(C>>2)&1, jm=C&3, laned=((C>>3)&3)*16+q*4+j
  const unsigned C = (unsigned)hcol;
  const unsigned sbase = ((C >> 8) * 8 + ((C >> 5) & 7)) * 512 + ((C >> 2) & 1) * 256 +
                         (((C >> 3) & 3) * 16 + q * 4) * 4 + (C & 3);
  unsigned* spA = hb  + sbase;    // row j store at + j*4
  unsigned* spB = hrb + sbase;

  const f32x4 z4 = {0.f, 0.f, 0.f, 0.f};
  f32x4 hreg = z4, zreg = z4;
  bool dead = false;

  for (int t = 0; t < TT; ++t) {
    // ---------------- phase A: h update ----------------
    unsigned short xh_u[4];
#pragma unroll
    for (int j = 0; j < 4; ++j)
      xh_u[j] = XH[((size_t)t * BB + brow0 + j) * HH + hcol];

    f32x4 acc[4] = {z4, z4, z4, z4};
    if (t > 0) {
      u32x4 a[8];
      load_validated(rpA, (unsigned)t, dead, a);
#pragma unroll
      for (int k = 0; k < 8; ++k) {
        s16x8 av = as16(a[k]);
#pragma unroll
        for (int ct = 0; ct < 4; ++ct)
          acc[ct] = MFMA16(av, as16(wh[ct][k]), acc[ct]);
      }
    }
#pragma unroll
    for (int ct = 0; ct < 4; ++ct) redA[(w * 4 + ct) * 64 + lane] = acc[ct];
    __syncthreads();
    f32x4 S = redA[(0 * 4 + w) * 64 + lane];
    S += redA[(1 * 4 + w) * 64 + lane];
    S += redA[(2 * 4 + w) * 64 + lane];
    S += redA[(3 * 4 + w) * 64 + lane];

    const unsigned tagn = (unsigned)(t + 1);
    if (t == TT - 1) {
#pragma unroll
      for (int j = 0; j < 4; ++j) {
        float pre = S[j] + bf2f(xh_u[j]);
        float ht = tanh_fast(pre);
        hreg[j] = zreg[j] * hreg[j] + (1.f - zreg[j]) * ht;
      }
      break;
    }
#pragma unroll
    for (int j = 0; j < 4; ++j) {
      float pre = S[j] + bf2f(xh_u[j]);
      float ht = tanh_fast(pre);
      float hn = zreg[j] * hreg[j] + (1.f - zreg[j]) * ht;
      hreg[j] = hn;
      st_dw(spA + j * 4, ((unsigned)f2bf(hn) << 16) | tagn);
    }

    // ---------------- phase B: gates ----------------
    unsigned short xz_u[4], xr_u[4];
#pragma unroll
    for (int j = 0; j < 4; ++j) {
      xz_u[j] = XZ[((size_t)t * BB + brow0 + j) * HH + hcol];
      xr_u[j] = XR[((size_t)t * BB + brow0 + j) * HH + hcol];
    }
    u32x4 b[8];
    load_validated(rpB, tagn, dead, b);

    f32x4 az[4] = {z4, z4, z4, z4};
    f32x4 ar[4] = {z4, z4, z4, z4};
#pragma unroll
    for (int ct = 0; ct < 4; ++ct) {
      u32x4 vrk[8];
#pragma unroll
      for (int k = 0; k < 8; ++k)
        vrk[k] = *(const u32x4*)(Vrp + (((size_t)(c4 + ct) * 32 + kw + k) * 64 + lane) * 8);
#pragma unroll
      for (int k = 0; k < 8; ++k)
        az[ct] = MFMA16(as16(b[k]), as16(vz[ct][k]), az[ct]);
#pragma unroll
      for (int k = 0; k < 8; ++k)
        ar[ct] = MFMA16(as16(b[k]), as16(vrk[k]), ar[ct]);
    }
#pragma unroll
    for (int ct = 0; ct < 4; ++ct) {
      redB[(w * 4 + ct) * 64 + lane] = az[ct];
      redC[(w * 4 + ct) * 64 + lane] = ar[ct];
    }
    __syncthreads();
    f32x4 Sz = redB[(0 * 4 + w) * 64 + lane];
    Sz += redB[(1 * 4 + w) * 64 + lane];
    Sz += redB[(2 * 4 + w) * 64 + lane];
    Sz += redB[(3 * 4 + w) * 64 + lane];
    f32x4 Sr = redC[(0 * 4 + w) * 64 + lane];
    Sr += redC[(1 * 4 + w) * 64 + lane];
    Sr += redC[(2 * 4 + w) * 64 + lane];
    Sr += redC[(3 * 4 + w) * 64 + lane];

#pragma unroll
    for (int j = 0; j < 4; ++j) {
      float zv = sigmoid_fast(Sz[j] + bf2f(xz_u[j]));
      float rv = sigmoid_fast(Sr[j] + bf2f(xr_u[j]));
      zreg[j] = zv;
      st_dw(spB + j * 4, ((unsigned)f2bf(rv * hreg[j]) << 16) | tagn);
    }
  }

  // epilogue: final h fp32 (plain stores; visible at kernel boundary)
#pragma unroll
  for (int j = 0; j < 4; ++j)
    hfinal[(size_t)(brow0 + j) * HH + hcol] = hreg[j];
}

// ============================================================================
// K5: out[b][o] = dot(h[b,:], Wo[o,:]) + bo[o]   (fp32)
// ============================================================================
__global__ void __launch_bounds__(256) k_out(const float* __restrict__ hf,
                                             const float* __restrict__ Wo,
                                             const float* __restrict__ bo,
                                             float* __restrict__ out) {
  __shared__ float hs[HH];
  const int b = blockIdx.x, tid = threadIdx.x;
  *(f32x4*)&hs[tid * 4] = *(const f32x4*)(hf + (size_t)b * HH + tid * 4);
  __syncthreads();
  float acc = bo[tid];
  const f32x4* wr = (const f32x4*)(Wo + (size_t)tid * HH);
#pragma unroll 8
  for (int k = 0; k < HH / 4; ++k) {
    f32x4 wv = wr[k];
    f32x4 hv = *(const f32x4*)&hs[k * 4];
    acc += wv[0] * hv[0] + wv[1] * hv[1] + wv[2] * hv[2] + wv[3] * hv[3];
  }
  out[(size_t)b * NOUT + tid] = acc;
}

// ============================================================================
extern "C" void kernel_launch(void* const* d_in, const int* in_sizes, int n_in,
                              void* d_out, int out_size, void* d_ws, size_t ws_size,
                              hipStream_t stream) {
  (void)in_sizes; (void)n_in; (void)out_size; (void)ws_size;
  const float* X  = (const float*)d_in[0];
  const float* Wx = (const float*)d_in[1];
  const float* bx = (const float*)d_in[2];
  const float* Wh = (const float*)d_in[3];
  const float* Uz = (const float*)d_in[4];
  const float* bz = (const float*)d_in[5];
  const float* Vz = (const float*)d_in[6];
  const float* Ur = (const float*)d_in[7];
  const float* br = (const float*)d_in[8];
  const float* Vr = (const float*)d_in[9];
  const float* Wo = (const float*)d_in[10];
  const float* bo = (const float*)d_in[11];

  char* ws = (char*)d_ws;
  unsigned short* XHp = (unsigned short*)(ws + OFF_XH);
  unsigned short* XZp = (unsigned short*)(ws + OFF_XZ);
  unsigned short* XRp = (unsigned short*)(ws + OFF_XR);
  unsigned short* Xb  = (unsigned short*)(ws + OFF_XB);
  unsigned short* Whp = (unsigned short*)(ws + OFF_WHP);
  unsigned short* Vzp = (unsigned short*)(ws + OFF_VZP);
  unsigned short* Vrp = (unsigned short*)(ws + OFF_VRP);
  unsigned short* Wxp = (unsigned short*)(ws + OFF_WXP);
  unsigned short* Uzp = (unsigned short*)(ws + OFF_UZP);
  unsigned short* Urp = (unsigned short*)(ws + OFF_URP);
  unsigned* hbp  = (unsigned*)(ws + OFF_HB);
  unsigned* hrbp = (unsigned*)(ws + OFF_HRB);
  float* hfp = (float*)(ws + OFF_HF);

  k_convert_x<<<8192, 256, 0, stream>>>(X, Xb);
  k_pack_w<<<dim3(512, 6), 256, 0, stream>>>(Wh, Vz, Vr, Wx, Uz, Ur,
                                             Whp, Vzp, Vrp, Wxp, Uzp, Urp);
  k_proj<<<dim3(512, 16, 3), 256, 0, stream>>>(Xb, Wxp, Uzp, Urp, bx, bz, br,
                                               XHp, XZp, XRp);
  k_scan<<<64, 256, 0, stream>>>(XHp, XZp, XRp, Whp, Vzp, Vrp,
                                 hbp, hrbp, hfp);
  k_out<<<64, 256, 0, stream>>>(hfp, Wo, bo, (float*)d_out);
}

// Round 5
// 3797.017 us; speedup vs baseline: 1.6090x; 1.0627x over previous
//
#include <hip/hip_runtime.h>

// ============================================================================
// GRU_29300266893722  (B=64, T=512, IN=256, H=1024, OUT=256)  -- MI355X gfx950
//
// R8: R5/R7 protocol (tag-in-data, sc0sc1, fragment-major exchange; best
// measured 3752us k_scan) with the critical path between exchanges shortened:
//  (1) z-GEMM DEFERRED: phase B computes r only, stores r*h immediately
//      (the value every other block polls for), THEN computes z-partials;
//      the z reduce+sigmoid is deferred into phase A(t+1) after its existing
//      __syncthreads (no extra barrier; xz carried in regs). z is not
//      consumed until phase A(t+1), so this is pure critical-path removal.
//  (2) Vr PREFETCH: load_validated's "memory" clobber pins the vrk loads
//      below the poll; prefetching ct=0's 8 frags before the poll hides
//      their L2 latency under the spin.
// LDS race audit: redB written phase B(t), read phase A(t+1) after syncA;
// next redB write is behind syncB(t+1). 2 barriers/step as before.
// Design-space notes: R4 atomics +1.8ms; R6 co-XCD+plain WRONG; R6.2
// co-XCD+sc0 +57% (store-visibility lag, not load latency); R5 = optimum.
// ============================================================================

#define BB 64
#define TT 512
#define KIN 256
#define HH 1024
#define NOUT 256

typedef float  f32x4 __attribute__((ext_vector_type(4)));
typedef short  s16x8 __attribute__((ext_vector_type(8)));
typedef unsigned int u32x4 __attribute__((ext_vector_type(4)));
typedef unsigned short u16x4 __attribute__((ext_vector_type(4)));

#define MFMA16(a, b, c) __builtin_amdgcn_mfma_f32_16x16x32_bf16((a), (b), (c), 0, 0, 0)

static __device__ __forceinline__ s16x8 as16(u32x4 v) { return __builtin_bit_cast(s16x8, v); }

static __device__ __forceinline__ unsigned short f2bf(float f) {
  unsigned u = __float_as_uint(f);
  u += 0x7FFFu + ((u >> 16) & 1u);   // round-to-nearest-even
  return (unsigned short)(u >> 16);
}
static __device__ __forceinline__ float bf2f(unsigned short h) {
  return __uint_as_float(((unsigned)h) << 16);
}

static __device__ __forceinline__ float tanh_fast(float x) {
  float xc = fminf(fmaxf(x, -15.f), 15.f);
  float e = __expf(2.f * xc);
  return (e - 1.f) / (e + 1.f);
}
static __device__ __forceinline__ float sigmoid_fast(float x) {
  float xc = fminf(fmaxf(x, -30.f), 30.f);
  return 1.f / (1.f + __expf(-xc));
}

// ---- device-scope (IF-coherent) access helpers -----------------------------
static __device__ __forceinline__ void st_dw(unsigned* p, unsigned v) {
  asm volatile("global_store_dword %0, %1, off sc0 sc1" :: "v"(p), "v"(v) : "memory");
}
template <int OFF>
static __device__ __forceinline__ void ld128o(u32x4& d, const unsigned* p) {
  asm volatile("global_load_dwordx4 %0, %1, off offset:%2 sc0 sc1"
               : "=v"(d) : "v"(p), "i"(OFF));
}
static __device__ __forceinline__ void tie16(u32x4& a0, u32x4& a1, u32x4& a2, u32x4& a3,
                                             u32x4& a4, u32x4& a5, u32x4& a6, u32x4& a7,
                                             u32x4& a8, u32x4& a9, u32x4& aA, u32x4& aB,
                                             u32x4& aC, u32x4& aD, u32x4& aE, u32x4& aF) {
  asm volatile("s_waitcnt vmcnt(0)"
               : "+v"(a0), "+v"(a1), "+v"(a2), "+v"(a3),
                 "+v"(a4), "+v"(a5), "+v"(a6), "+v"(a7),
                 "+v"(a8), "+v"(a9), "+v"(aA), "+v"(aB),
                 "+v"(aC), "+v"(aD), "+v"(aE), "+v"(aF)
               :: "memory");
}

// pack two tagged-dword quads (cols j0..3, j4..7) into one bf16x8 frag quad
static __device__ __forceinline__ unsigned pk(unsigned hi, unsigned lo) {
  return __builtin_amdgcn_perm(hi, lo, 0x07060302u);
}
static __device__ __forceinline__ u32x4 pack_frag(u32x4 a, u32x4 b) {
  u32x4 r;
  r.x = pk(a.y, a.x); r.y = pk(a.w, a.z);
  r.z = pk(b.y, b.x); r.w = pk(b.w, b.z);
  return r;
}

// Validated A-operand load, fragment-major layout. rp0 = buf + w*4096 + lane*4
// (dwords). Frag k: lo at k*2048B, hi at +1024B; 4 base pointers keep the
// 13-bit signed immediate offsets in range. Retries until all tags match.
static __device__ __forceinline__ void load_validated(
    const unsigned* rp0, unsigned tag, bool& dead, u32x4 (&a)[8]) {
  const unsigned* p1 = rp0 + 1024;
  const unsigned* p2 = rp0 + 2048;
  const unsigned* p3 = rp0 + 3072;
  u32x4 r0, r1, r2, r3, r4, r5, r6, r7, r8, r9, rA, rB, rC, rD, rE, rF;
  int guard = 0;
  while (true) {
    ld128o<0>(r0, rp0); ld128o<1024>(r1, rp0); ld128o<2048>(r2, rp0); ld128o<3072>(r3, rp0);
    ld128o<0>(r4, p1);  ld128o<1024>(r5, p1);  ld128o<2048>(r6, p1);  ld128o<3072>(r7, p1);
    ld128o<0>(r8, p2);  ld128o<1024>(r9, p2);  ld128o<2048>(rA, p2);  ld128o<3072>(rB, p2);
    ld128o<0>(rC, p3);  ld128o<1024>(rD, p3);  ld128o<2048>(rE, p3);  ld128o<3072>(rF, p3);
    tie16(r0, r1, r2, r3, r4, r5, r6, r7, r8, r9, rA, rB, rC, rD, rE, rF);
    unsigned bad = 0;
#define CHK(R) bad |= (R.x ^ tag) | (R.y ^ tag) | (R.z ^ tag) | (R.w ^ tag)
    CHK(r0); CHK(r1); CHK(r2); CHK(r3); CHK(r4); CHK(r5); CHK(r6); CHK(r7);
    CHK(r8); CHK(r9); CHK(rA); CHK(rB); CHK(rC); CHK(rD); CHK(rE); CHK(rF);
#undef CHK
    bad &= 0xFFFFu;
    if (__all(bad == 0)) break;
    if (dead || ++guard > 4096) { dead = true; break; }
  }
  a[0] = pack_frag(r0, r1); a[1] = pack_frag(r2, r3);
  a[2] = pack_frag(r4, r5); a[3] = pack_frag(r6, r7);
  a[4] = pack_frag(r8, r9); a[5] = pack_frag(rA, rB);
  a[6] = pack_frag(rC, rD); a[7] = pack_frag(rE, rF);
}

// ---- workspace layout ------------------------------------------------------
static constexpr size_t SZ_XP   = (size_t)TT * BB * HH * 2;       // 64 MB
static constexpr size_t OFF_XH  = 0;
static constexpr size_t OFF_XZ  = OFF_XH + SZ_XP;
static constexpr size_t OFF_XR  = OFF_XZ + SZ_XP;
static constexpr size_t OFF_XB  = OFF_XR + SZ_XP;                 // X bf16
static constexpr size_t OFF_WHP = OFF_XB + (size_t)BB * TT * KIN * 2;
static constexpr size_t OFF_VZP = OFF_WHP + (size_t)HH * HH * 2;
static constexpr size_t OFF_VRP = OFF_VZP + (size_t)HH * HH * 2;
static constexpr size_t OFF_WXP = OFF_VRP + (size_t)HH * HH * 2;
static constexpr size_t OFF_UZP = OFF_WXP + (size_t)HH * KIN * 2;
static constexpr size_t OFF_URP = OFF_UZP + (size_t)HH * KIN * 2;
static constexpr size_t OFF_HB  = OFF_URP + (size_t)HH * KIN * 2; // 4*16*1024 tagged dwords
static constexpr size_t OFF_HRB = OFF_HB + (size_t)4 * 16 * HH * 4;
static constexpr size_t OFF_HF  = OFF_HRB + (size_t)4 * 16 * HH * 4;  // final h fp32

// ============================================================================
// K1: X fp32 -> bf16
// ============================================================================
__global__ void __launch_bounds__(256) k_convert_x(const float* __restrict__ X,
                                                   unsigned short* __restrict__ Xb) {
  size_t i = ((size_t)blockIdx.x * 256 + threadIdx.x) * 4;
  f32x4 v = *(const f32x4*)(X + i);
  u16x4 o = { f2bf(v[0]), f2bf(v[1]), f2bf(v[2]), f2bf(v[3]) };
  *(u16x4*)(Xb + i) = o;
}

// ============================================================================
// K2: pack weights W[1024][K] fp32 -> bf16 MFMA B-fragment layout
// ============================================================================
__global__ void __launch_bounds__(256) k_pack_w(
    const float* __restrict__ Wh, const float* __restrict__ Vz, const float* __restrict__ Vr,
    const float* __restrict__ Wx, const float* __restrict__ Uz, const float* __restrict__ Ur,
    unsigned short* __restrict__ Whp, unsigned short* __restrict__ Vzp, unsigned short* __restrict__ Vrp,
    unsigned short* __restrict__ Wxp, unsigned short* __restrict__ Uzp, unsigned short* __restrict__ Urp) {
  int z = blockIdx.y;
  const float* src; unsigned short* dst; int K;
  switch (z) {
    case 0: src = Wh; dst = Whp; K = 1024; break;
    case 1: src = Vz; dst = Vzp; K = 1024; break;
    case 2: src = Vr; dst = Vrp; K = 1024; break;
    case 3: src = Wx; dst = Wxp; K = 256;  break;
    case 4: src = Uz; dst = Uzp; K = 256;  break;
    default: src = Ur; dst = Urp; K = 256; break;
  }
  int KK = K >> 5;
  int total = 64 * KK * 64;
  int tau = blockIdx.x * 256 + threadIdx.x;
  if (tau >= total) return;
  int lane = tau & 63;
  int kk = (tau >> 6) % KK;
  int ct = tau / (KK * 64);
  int q = lane >> 4, cl = lane & 15;
  const float* s = src + (size_t)(ct * 16 + cl) * K + kk * 32 + q * 8;
  f32x4 v0 = *(const f32x4*)s;
  f32x4 v1 = *(const f32x4*)(s + 4);
  u32x4 o;
  o.x = (unsigned)f2bf(v0[0]) | ((unsigned)f2bf(v0[1]) << 16);
  o.y = (unsigned)f2bf(v0[2]) | ((unsigned)f2bf(v0[3]) << 16);
  o.z = (unsigned)f2bf(v1[0]) | ((unsigned)f2bf(v1[1]) << 16);
  o.w = (unsigned)f2bf(v1[2]) | ((unsigned)f2bf(v1[3]) << 16);
  *(u32x4*)(dst + (size_t)tau * 8) = o;
}

// ============================================================================
// K3: XH/XZ/XR[t][b][h] (bf16) = X @ {Wx,Uz,Ur}^T + bias.  grid (512,16,3).
// ============================================================================
__global__ void __launch_bounds__(256) k_proj(
    const unsigned short* __restrict__ Xb,
    const unsigned short* __restrict__ Wxp, const unsigned short* __restrict__ Uzp,
    const unsigned short* __restrict__ Urp,
    const float* __restrict__ bx, const float* __restrict__ bz, const float* __restrict__ br,
    unsigned short* __restrict__ XH, unsigned short* __restrict__ XZ, unsigned short* __restrict__ XR) {
  __shared__ u32x4 As[4 * 8 * 64];  // 32 KB
  const int tid = threadIdx.x;
  const int mb = blockIdx.x, cb = blockIdx.y, mu = blockIdx.z;

#pragma unroll
  for (int i = 0; i < 8; ++i) {
    int fid = i * 256 + tid;
    int lane = fid & 63, kk = (fid >> 6) & 7, rt = fid >> 9;
    int q = lane >> 4, cl = lane & 15;
    int mrow = mb * 64 + rt * 16 + cl;
    As[fid] = *(const u32x4*)(Xb + (size_t)mrow * KIN + kk * 32 + q * 8);
  }
  __syncthreads();

  const int lane = tid & 63, w = tid >> 6;
  const int q = lane >> 4, cl = lane & 15;
  const unsigned short* Bp = (mu == 0) ? Wxp : (mu == 1) ? Uzp : Urp;
  const float* bias        = (mu == 0) ? bx  : (mu == 1) ? bz  : br;
  unsigned short* Dst      = (mu == 0) ? XH  : (mu == 1) ? XZ  : XR;

  f32x4 z4 = {0.f, 0.f, 0.f, 0.f};
  f32x4 acc[4] = {z4, z4, z4, z4};
  const int ctg = cb * 4 + w;
#pragma unroll
  for (int kk = 0; kk < 8; ++kk) {
    u32x4 b = *(const u32x4*)(Bp + ((size_t)(ctg * 8 + kk) * 64 + lane) * 8);
#pragma unroll
    for (int rt = 0; rt < 4; ++rt)
      acc[rt] = MFMA16(as16(As[(rt * 8 + kk) * 64 + lane]), as16(b), acc[rt]);
  }
  const int col = cb * 64 + w * 16 + cl;
  const float bv = bias[col];
#pragma unroll
  for (int rt = 0; rt < 4; ++rt) {
#pragma unroll
    for (int j = 0; j < 4; ++j) {
      int m = mb * 64 + rt * 16 + q * 4 + j;   // m = b*512 + t
      int t = m & (TT - 1), b = m >> 9;
      Dst[((size_t)t * BB + b) * HH + col] = f2bf(acc[rt][j] + bv);
    }
  }
}

// ============================================================================
// K4: persistent scan, tag-in-data, fragment-major exchange buffers.
//   64 blocks x 256 threads. chain g = blk>>4 (rows 16g..16g+15),
//   col-block c = blk&15 (cols 64c..64c+63). wave w: K-slice [256w,256w+256),
//   owns state for cols c*64+w*16+cl, rows q*4+j (C/D layout).
//   R8: z deferred off the critical path; Vr ct=0 prefetched above the poll.
// ============================================================================
__global__ void __launch_bounds__(256, 1) k_scan(
    const unsigned short* __restrict__ XH, const unsigned short* __restrict__ XZ,
    const unsigned short* __restrict__ XR,
    const unsigned short* __restrict__ Whp, const unsigned short* __restrict__ Vzp,
    const unsigned short* __restrict__ Vrp,
    unsigned* __restrict__ hb32all, unsigned* __restrict__ hrb32all,
    float* __restrict__ hfinal) {
  __shared__ f32x4 redA[16 * 64];  // 16 KB
  __shared__ f32x4 redB[16 * 64];  // 16 KB  (z-partials; reduced next step)
  __shared__ f32x4 redC[16 * 64];  // 16 KB

  const int tid = threadIdx.x;
  const int lane = tid & 63, w = tid >> 6;
  const int q = lane >> 4, cl = lane & 15;
  const int blk = blockIdx.x;
  const int g = blk >> 4, c = blk & 15;   // chain, col-block
  const int c4 = c * 4, kw = w * 8;

  unsigned* hb  = hb32all  + (size_t)g * 16 * HH;
  unsigned* hrb = hrb32all + (size_t)g * 16 * HH;

  // resident weight fragments: Wh + Vz (256 VGPRs); Vr streamed per step
  u32x4 wh[4][8], vz[4][8];
#pragma unroll
  for (int ct = 0; ct < 4; ++ct)
#pragma unroll
    for (int k = 0; k < 8; ++k) {
      size_t fi = (((size_t)(c4 + ct) * 32 + kw + k) * 64 + lane) * 8;
      wh[ct][k] = *(const u32x4*)(Whp + fi);
      vz[ct][k] = *(const u32x4*)(Vzp + fi);
    }

  const int hcol = c * 64 + w * 16 + cl;         // owned output column
  const int brow0 = g * 16 + q * 4;              // owned batch rows (+j)

  // consumer read bases (fragment-major): buf + w*4096 + lane*4 dwords
  const unsigned* rpA = hrb + w * 4096 + lane * 4;
  const unsigned* rpB = hb  + w * 4096 + lane * 4;
  // producer store bases: dword idx = (wd*8+kd)*512 + half*256 + laned*4 + jm
  //   wd=C>>8, kd=(C>>5)&7, half=(C>>2)&1, jm=C&3, laned=((C>>3)&3)*16+q*4+j
  const unsigned C = (unsigned)hcol;
  const unsigned sbase = ((C >> 8) * 8 + ((C >> 5) & 7)) * 512 + ((C >> 2) & 1) * 256 +
                         (((C >> 3) & 3) * 16 + q * 4) * 4 + (C & 3);
  unsigned* spA = hb  + sbase;    // row j store at + j*4
  unsigned* spB = hrb + sbase;

  const f32x4 z4 = {0.f, 0.f, 0.f, 0.f};
  f32x4 hreg = z4, zreg = z4;
  unsigned short xz_u[4] = {0, 0, 0, 0};  // carried across steps (deferred z)
  bool dead = false;

  for (int t = 0; t < TT; ++t) {
    // ---------------- phase A: h update ----------------
    unsigned short xh_u[4];
#pragma unroll
    for (int j = 0; j < 4; ++j)
      xh_u[j] = XH[((size_t)t * BB + brow0 + j) * HH + hcol];

    f32x4 acc[4] = {z4, z4, z4, z4};
    if (t > 0) {
      u32x4 a[8];
      load_validated(rpA, (unsigned)t, dead, a);
#pragma unroll
      for (int k = 0; k < 8; ++k) {
        s16x8 av = as16(a[k]);
#pragma unroll
        for (int ct = 0; ct < 4; ++ct)
          acc[ct] = MFMA16(av, as16(wh[ct][k]), acc[ct]);
      }
    }
#pragma unroll
    for (int ct = 0; ct < 4; ++ct) redA[(w * 4 + ct) * 64 + lane] = acc[ct];
    __syncthreads();
    f32x4 S = redA[(0 * 4 + w) * 64 + lane];
    S += redA[(1 * 4 + w) * 64 + lane];
    S += redA[(2 * 4 + w) * 64 + lane];
    S += redA[(3 * 4 + w) * 64 + lane];

    // deferred z from phase B(t-1): redB partials are barrier-covered by the
    // __syncthreads above (all waves wrote redB before reaching it).
    if (t > 0) {
      f32x4 Sz = redB[(0 * 4 + w) * 64 + lane];
      Sz += redB[(1 * 4 + w) * 64 + lane];
      Sz += redB[(2 * 4 + w) * 64 + lane];
      Sz += redB[(3 * 4 + w) * 64 + lane];
#pragma unroll
      for (int j = 0; j < 4; ++j)
        zreg[j] = sigmoid_fast(Sz[j] + bf2f(xz_u[j]));
    }

    float hn[4];
#pragma unroll
    for (int j = 0; j < 4; ++j) {
      float pre = S[j] + bf2f(xh_u[j]);
      float ht = tanh_fast(pre);
      hn[j] = zreg[j] * hreg[j] + (1.f - zreg[j]) * ht;
      hreg[j] = hn[j];
    }
    if (t == TT - 1) break;

    const unsigned tagn = (unsigned)(t + 1);
#pragma unroll
    for (int j = 0; j < 4; ++j)
      st_dw(spA + j * 4, ((unsigned)f2bf(hn[j]) << 16) | tagn);

    // ---------------- phase B: gates (r first, z deferred) ----------------
    unsigned short xr_u[4];
#pragma unroll
    for (int j = 0; j < 4; ++j) {
      xz_u[j] = XZ[((size_t)t * BB + brow0 + j) * HH + hcol];
      xr_u[j] = XR[((size_t)t * BB + brow0 + j) * HH + hcol];
    }
    // prefetch Vr ct=0 above the poll (its "memory" clobber pins loads below)
    u32x4 vr0[8];
#pragma unroll
    for (int k = 0; k < 8; ++k)
      vr0[k] = *(const u32x4*)(Vrp + (((size_t)(c4 + 0) * 32 + kw + k) * 64 + lane) * 8);

    u32x4 b[8];
    load_validated(rpB, tagn, dead, b);

    // r-GEMM only (critical path)
    f32x4 ar[4] = {z4, z4, z4, z4};
#pragma unroll
    for (int k = 0; k < 8; ++k)
      ar[0] = MFMA16(as16(b[k]), as16(vr0[k]), ar[0]);
#pragma unroll
    for (int ct = 1; ct < 4; ++ct) {
      u32x4 vrk[8];
#pragma unroll
      for (int k = 0; k < 8; ++k)
        vrk[k] = *(const u32x4*)(Vrp + (((size_t)(c4 + ct) * 32 + kw + k) * 64 + lane) * 8);
#pragma unroll
      for (int k = 0; k < 8; ++k)
        ar[ct] = MFMA16(as16(b[k]), as16(vrk[k]), ar[ct]);
    }
#pragma unroll
    for (int ct = 0; ct < 4; ++ct) redC[(w * 4 + ct) * 64 + lane] = ar[ct];
    __syncthreads();
    f32x4 Sr = redC[(0 * 4 + w) * 64 + lane];
    Sr += redC[(1 * 4 + w) * 64 + lane];
    Sr += redC[(2 * 4 + w) * 64 + lane];
    Sr += redC[(3 * 4 + w) * 64 + lane];

    float rh[4];
#pragma unroll
    for (int j = 0; j < 4; ++j) {
      float rv = sigmoid_fast(Sr[j] + bf2f(xr_u[j]));
      rh[j] = rv * hreg[j];
    }
#pragma unroll
    for (int j = 0; j < 4; ++j)
      st_dw(spB + j * 4, ((unsigned)f2bf(rh[j]) << 16) | tagn);

    // z-partials (off critical path; reduce deferred to phase A(t+1))
    f32x4 az[4] = {z4, z4, z4, z4};
#pragma unroll
    for (int ct = 0; ct < 4; ++ct)
#pragma unroll
      for (int k = 0; k < 8; ++k)
        az[ct] = MFMA16(as16(b[k]), as16(vz[ct][k]), az[ct]);
#pragma unroll
    for (int ct = 0; ct < 4; ++ct) redB[(w * 4 + ct) * 64 + lane] = az[ct];
    // no barrier here: phase A(t+1)'s __syncthreads covers the redB writes
  }

  // epilogue: final h fp32 (plain stores; visible at kernel boundary)
#pragma unroll
  for (int j = 0; j < 4; ++j)
    hfinal[(size_t)(brow0 + j) * HH + hcol] = hreg[j];
}

// ============================================================================
// K5: out[b][o] = dot(h[b,:], Wo[o,:]) + bo[o]   (fp32)
// ============================================================================
__global__ void __launch_bounds__(256) k_out(const float* __restrict__ hf,
                                             const float* __restrict__ Wo,
                                             const float* __restrict__ bo,
                                             float* __restrict__ out) {
  __shared__ float hs[HH];
  const int b = blockIdx.x, tid = threadIdx.x;
  *(f32x4*)&hs[tid * 4] = *(const f32x4*)(hf + (size_t)b * HH + tid * 4);
  __syncthreads();
  float acc = bo[tid];
  const f32x4* wr = (const f32x4*)(Wo + (size_t)tid * HH);
#pragma unroll 8
  for (int k = 0; k < HH / 4; ++k) {
    f32x4 wv = wr[k];
    f32x4 hv = *(const f32x4*)&hs[k * 4];
    acc += wv[0] * hv[0] + wv[1] * hv[1] + wv[2] * hv[2] + wv[3] * hv[3];
  }
  out[(size_t)b * NOUT + tid] = acc;
}

// ============================================================================
extern "C" void kernel_launch(void* const* d_in, const int* in_sizes, int n_in,
                              void* d_out, int out_size, void* d_ws, size_t ws_size,
                              hipStream_t stream) {
  (void)in_sizes; (void)n_in; (void)out_size; (void)ws_size;
  const float* X  = (const float*)d_in[0];
  const float* Wx = (const float*)d_in[1];
  const float* bx = (const float*)d_in[2];
  const float* Wh = (const float*)d_in[3];
  const float* Uz = (const float*)d_in[4];
  const float* bz = (const float*)d_in[5];
  const float* Vz = (const float*)d_in[6];
  const float* Ur = (const float*)d_in[7];
  const float* br = (const float*)d_in[8];
  const float* Vr = (const float*)d_in[9];
  const float* Wo = (const float*)d_in[10];
  const float* bo = (const float*)d_in[11];

  char* ws = (char*)d_ws;
  unsigned short* XHp = (unsigned short*)(ws + OFF_XH);
  unsigned short* XZp = (unsigned short*)(ws + OFF_XZ);
  unsigned short* XRp = (unsigned short*)(ws + OFF_XR);
  unsigned short* Xb  = (unsigned short*)(ws + OFF_XB);
  unsigned short* Whp = (unsigned short*)(ws + OFF_WHP);
  unsigned short* Vzp = (unsigned short*)(ws + OFF_VZP);
  unsigned short* Vrp = (unsigned short*)(ws + OFF_VRP);
  unsigned short* Wxp = (unsigned short*)(ws + OFF_WXP);
  unsigned short* Uzp = (unsigned short*)(ws + OFF_UZP);
  unsigned short* Urp = (unsigned short*)(ws + OFF_URP);
  unsigned* hbp  = (unsigned*)(ws + OFF_HB);
  unsigned* hrbp = (unsigned*)(ws + OFF_HRB);
  float* hfp = (float*)(ws + OFF_HF);

  k_convert_x<<<8192, 256, 0, stream>>>(X, Xb);
  k_pack_w<<<dim3(512, 6), 256, 0, stream>>>(Wh, Vz, Vr, Wx, Uz, Ur,
                                             Whp, Vzp, Vrp, Wxp, Uzp, Urp);
  k_proj<<<dim3(512, 16, 3), 256, 0, stream>>>(Xb, Wxp, Uzp, Urp, bx, bz, br,
                                               XHp, XZp, XRp);
  k_scan<<<64, 256, 0, stream>>>(XHp, XZp, XRp, Whp, Vzp, Vrp,
                                 hbp, hrbp, hfp);
  k_out<<<64, 256, 0, stream>>>(hfp, Wo, bo, (float*)d_out);
}

// Round 7
// 3789.617 us; speedup vs baseline: 1.6121x; 1.0020x over previous
//
#include <hip/hip_runtime.h>

// ============================================================================
// GRU_29300266893722  (B=64, T=512, IN=256, H=1024, OUT=256)  -- MI355X gfx950
//
// R9.1 = R8 + exponential backoff in the poll loop (R9 compile-fix:
// s_sleep arg must be a literal -> two constant calls behind a branch).
// Evidence: VALUBusy scaled to the 64 active CUs ~22% => ~3.7k VALU-cy/step,
// only explicable by MANY tag-check rounds (~10-25/phase); FETCH shows polls
// are L3-served (cheap, invisible), so heavy spinning is consistent. Theory:
// posted sc0sc1 stores drain slowly through the IF coherence point WHILE 256
// waves flood it with 16KB poll rounds -- polls contend with the very store
// drains they await (convoy). R6.2 corroborates: fixing load-side latency
// (FETCH 1.29G->0.34G) didn't help because store visibility is the limiter.
// Fix attempt: back off on failed rounds (attempt 1 no sleep; then s_sleep
// 2 -> 4, i.e. ~128-256cy vs ~700cy round). One-variable change vs R8.
//   If contention-dominated: k_scan 3547 -> ~2900-3250us.
//   If store lag intrinsic: flat (protocol floor established).
// R8 retained: z-GEMM deferred off critical path (-5.5% measured), Vr ct=0
// prefetch above the poll. Design-space: R4 atomics +1.8ms; R6 plain/inv
// WRONG; R6.2 co-XCD sc0 +57%; R5 structure = base.
// ============================================================================

#define BB 64
#define TT 512
#define KIN 256
#define HH 1024
#define NOUT 256

typedef float  f32x4 __attribute__((ext_vector_type(4)));
typedef short  s16x8 __attribute__((ext_vector_type(8)));
typedef unsigned int u32x4 __attribute__((ext_vector_type(4)));
typedef unsigned short u16x4 __attribute__((ext_vector_type(4)));

#define MFMA16(a, b, c) __builtin_amdgcn_mfma_f32_16x16x32_bf16((a), (b), (c), 0, 0, 0)

static __device__ __forceinline__ s16x8 as16(u32x4 v) { return __builtin_bit_cast(s16x8, v); }

static __device__ __forceinline__ unsigned short f2bf(float f) {
  unsigned u = __float_as_uint(f);
  u += 0x7FFFu + ((u >> 16) & 1u);   // round-to-nearest-even
  return (unsigned short)(u >> 16);
}
static __device__ __forceinline__ float bf2f(unsigned short h) {
  return __uint_as_float(((unsigned)h) << 16);
}

static __device__ __forceinline__ float tanh_fast(float x) {
  float xc = fminf(fmaxf(x, -15.f), 15.f);
  float e = __expf(2.f * xc);
  return (e - 1.f) / (e + 1.f);
}
static __device__ __forceinline__ float sigmoid_fast(float x) {
  float xc = fminf(fmaxf(x, -30.f), 30.f);
  return 1.f / (1.f + __expf(-xc));
}

// ---- device-scope (IF-coherent) access helpers -----------------------------
static __device__ __forceinline__ void st_dw(unsigned* p, unsigned v) {
  asm volatile("global_store_dword %0, %1, off sc0 sc1" :: "v"(p), "v"(v) : "memory");
}
template <int OFF>
static __device__ __forceinline__ void ld128o(u32x4& d, const unsigned* p) {
  asm volatile("global_load_dwordx4 %0, %1, off offset:%2 sc0 sc1"
               : "=v"(d) : "v"(p), "i"(OFF));
}
static __device__ __forceinline__ void tie16(u32x4& a0, u32x4& a1, u32x4& a2, u32x4& a3,
                                             u32x4& a4, u32x4& a5, u32x4& a6, u32x4& a7,
                                             u32x4& a8, u32x4& a9, u32x4& aA, u32x4& aB,
                                             u32x4& aC, u32x4& aD, u32x4& aE, u32x4& aF) {
  asm volatile("s_waitcnt vmcnt(0)"
               : "+v"(a0), "+v"(a1), "+v"(a2), "+v"(a3),
                 "+v"(a4), "+v"(a5), "+v"(a6), "+v"(a7),
                 "+v"(a8), "+v"(a9), "+v"(aA), "+v"(aB),
                 "+v"(aC), "+v"(aD), "+v"(aE), "+v"(aF)
               :: "memory");
}

// pack two tagged-dword quads (cols j0..3, j4..7) into one bf16x8 frag quad
static __device__ __forceinline__ unsigned pk(unsigned hi, unsigned lo) {
  return __builtin_amdgcn_perm(hi, lo, 0x07060302u);
}
static __device__ __forceinline__ u32x4 pack_frag(u32x4 a, u32x4 b) {
  u32x4 r;
  r.x = pk(a.y, a.x); r.y = pk(a.w, a.z);
  r.z = pk(b.y, b.x); r.w = pk(b.w, b.z);
  return r;
}

// Validated A-operand load, fragment-major layout. rp0 = buf + w*4096 + lane*4
// (dwords). Frag k: lo at k*2048B, hi at +1024B; 4 base pointers keep the
// 13-bit signed immediate offsets in range. Retries until all tags match.
// R9.1: exponential backoff on failed rounds (attempt 1 hot; sleep 2 then 4;
// s_sleep needs a literal operand -> constant calls behind a branch).
static __device__ __forceinline__ void load_validated(
    const unsigned* rp0, unsigned tag, bool& dead, u32x4 (&a)[8]) {
  const unsigned* p1 = rp0 + 1024;
  const unsigned* p2 = rp0 + 2048;
  const unsigned* p3 = rp0 + 3072;
  u32x4 r0, r1, r2, r3, r4, r5, r6, r7, r8, r9, rA, rB, rC, rD, rE, rF;
  int guard = 0;
  while (true) {
    ld128o<0>(r0, rp0); ld128o<1024>(r1, rp0); ld128o<2048>(r2, rp0); ld128o<3072>(r3, rp0);
    ld128o<0>(r4, p1);  ld128o<1024>(r5, p1);  ld128o<2048>(r6, p1);  ld128o<3072>(r7, p1);
    ld128o<0>(r8, p2);  ld128o<1024>(r9, p2);  ld128o<2048>(rA, p2);  ld128o<3072>(rB, p2);
    ld128o<0>(rC, p3);  ld128o<1024>(rD, p3);  ld128o<2048>(rE, p3);  ld128o<3072>(rF, p3);
    tie16(r0, r1, r2, r3, r4, r5, r6, r7, r8, r9, rA, rB, rC, rD, rE, rF);
    unsigned bad = 0;
#define CHK(R) bad |= (R.x ^ tag) | (R.y ^ tag) | (R.z ^ tag) | (R.w ^ tag)
    CHK(r0); CHK(r1); CHK(r2); CHK(r3); CHK(r4); CHK(r5); CHK(r6); CHK(r7);
    CHK(r8); CHK(r9); CHK(rA); CHK(rB); CHK(rC); CHK(rD); CHK(rE); CHK(rF);
#undef CHK
    bad &= 0xFFFFu;
    if (__all(bad == 0)) break;
    if (dead || ++guard > 4096) { dead = true; break; }
    // backoff: reduce poll flood at the IF coherence point so producer
    // store drains stop contending with consumer polls (convoy breaker).
    if (guard > 1) {
      if (guard < 6) __builtin_amdgcn_s_sleep(2);
      else           __builtin_amdgcn_s_sleep(4);
    }
  }
  a[0] = pack_frag(r0, r1); a[1] = pack_frag(r2, r3);
  a[2] = pack_frag(r4, r5); a[3] = pack_frag(r6, r7);
  a[4] = pack_frag(r8, r9); a[5] = pack_frag(rA, rB);
  a[6] = pack_frag(rC, rD); a[7] = pack_frag(rE, rF);
}

// ---- workspace layout ------------------------------------------------------
static constexpr size_t SZ_XP   = (size_t)TT * BB * HH * 2;       // 64 MB
static constexpr size_t OFF_XH  = 0;
static constexpr size_t OFF_XZ  = OFF_XH + SZ_XP;
static constexpr size_t OFF_XR  = OFF_XZ + SZ_XP;
static constexpr size_t OFF_XB  = OFF_XR + SZ_XP;                 // X bf16
static constexpr size_t OFF_WHP = OFF_XB + (size_t)BB * TT * KIN * 2;
static constexpr size_t OFF_VZP = OFF_WHP + (size_t)HH * HH * 2;
static constexpr size_t OFF_VRP = OFF_VZP + (size_t)HH * HH * 2;
static constexpr size_t OFF_WXP = OFF_VRP + (size_t)HH * HH * 2;
static constexpr size_t OFF_UZP = OFF_WXP + (size_t)HH * KIN * 2;
static constexpr size_t OFF_URP = OFF_UZP + (size_t)HH * KIN * 2;
static constexpr size_t OFF_HB  = OFF_URP + (size_t)HH * KIN * 2; // 4*16*1024 tagged dwords
static constexpr size_t OFF_HRB = OFF_HB + (size_t)4 * 16 * HH * 4;
static constexpr size_t OFF_HF  = OFF_HRB + (size_t)4 * 16 * HH * 4;  // final h fp32

// ============================================================================
// K1: X fp32 -> bf16
// ============================================================================
__global__ void __launch_bounds__(256) k_convert_x(const float* __restrict__ X,
                                                   unsigned short* __restrict__ Xb) {
  size_t i = ((size_t)blockIdx.x * 256 + threadIdx.x) * 4;
  f32x4 v = *(const f32x4*)(X + i);
  u16x4 o = { f2bf(v[0]), f2bf(v[1]), f2bf(v[2]), f2bf(v[3]) };
  *(u16x4*)(Xb + i) = o;
}

// ============================================================================
// K2: pack weights W[1024][K] fp32 -> bf16 MFMA B-fragment layout
// ============================================================================
__global__ void __launch_bounds__(256) k_pack_w(
    const float* __restrict__ Wh, const float* __restrict__ Vz, const float* __restrict__ Vr,
    const float* __restrict__ Wx, const float* __restrict__ Uz, const float* __restrict__ Ur,
    unsigned short* __restrict__ Whp, unsigned short* __restrict__ Vzp, unsigned short* __restrict__ Vrp,
    unsigned short* __restrict__ Wxp, unsigned short* __restrict__ Uzp, unsigned short* __restrict__ Urp) {
  int z = blockIdx.y;
  const float* src; unsigned short* dst; int K;
  switch (z) {
    case 0: src = Wh; dst = Whp; K = 1024; break;
    case 1: src = Vz; dst = Vzp; K = 1024; break;
    case 2: src = Vr; dst = Vrp; K = 1024; break;
    case 3: src = Wx; dst = Wxp; K = 256;  break;
    case 4: src = Uz; dst = Uzp; K = 256;  break;
    default: src = Ur; dst = Urp; K = 256; break;
  }
  int KK = K >> 5;
  int total = 64 * KK * 64;
  int tau = blockIdx.x * 256 + threadIdx.x;
  if (tau >= total) return;
  int lane = tau & 63;
  int kk = (tau >> 6) % KK;
  int ct = tau / (KK * 64);
  int q = lane >> 4, cl = lane & 15;
  const float* s = src + (size_t)(ct * 16 + cl) * K + kk * 32 + q * 8;
  f32x4 v0 = *(const f32x4*)s;
  f32x4 v1 = *(const f32x4*)(s + 4);
  u32x4 o;
  o.x = (unsigned)f2bf(v0[0]) | ((unsigned)f2bf(v0[1]) << 16);
  o.y = (unsigned)f2bf(v0[2]) | ((unsigned)f2bf(v0[3]) << 16);
  o.z = (unsigned)f2bf(v1[0]) | ((unsigned)f2bf(v1[1]) << 16);
  o.w = (unsigned)f2bf(v1[2]) | ((unsigned)f2bf(v1[3]) << 16);
  *(u32x4*)(dst + (size_t)tau * 8) = o;
}

// ============================================================================
// K3: XH/XZ/XR[t][b][h] (bf16) = X @ {Wx,Uz,Ur}^T + bias.  grid (512,16,3).
// ============================================================================
__global__ void __launch_bounds__(256) k_proj(
    const unsigned short* __restrict__ Xb,
    const unsigned short* __restrict__ Wxp, const unsigned short* __restrict__ Uzp,
    const unsigned short* __restrict__ Urp,
    const float* __restrict__ bx, const float* __restrict__ bz, const float* __restrict__ br,
    unsigned short* __restrict__ XH, unsigned short* __restrict__ XZ, unsigned short* __restrict__ XR) {
  __shared__ u32x4 As[4 * 8 * 64];  // 32 KB
  const int tid = threadIdx.x;
  const int mb = blockIdx.x, cb = blockIdx.y, mu = blockIdx.z;

#pragma unroll
  for (int i = 0; i < 8; ++i) {
    int fid = i * 256 + tid;
    int lane = fid & 63, kk = (fid >> 6) & 7, rt = fid >> 9;
    int q = lane >> 4, cl = lane & 15;
    int mrow = mb * 64 + rt * 16 + cl;
    As[fid] = *(const u32x4*)(Xb + (size_t)mrow * KIN + kk * 32 + q * 8);
  }
  __syncthreads();

  const int lane = tid & 63, w = tid >> 6;
  const int q = lane >> 4, cl = lane & 15;
  const unsigned short* Bp = (mu == 0) ? Wxp : (mu == 1) ? Uzp : Urp;
  const float* bias        = (mu == 0) ? bx  : (mu == 1) ? bz  : br;
  unsigned short* Dst      = (mu == 0) ? XH  : (mu == 1) ? XZ  : XR;

  f32x4 z4 = {0.f, 0.f, 0.f, 0.f};
  f32x4 acc[4] = {z4, z4, z4, z4};
  const int ctg = cb * 4 + w;
#pragma unroll
  for (int kk = 0; kk < 8; ++kk) {
    u32x4 b = *(const u32x4*)(Bp + ((size_t)(ctg * 8 + kk) * 64 + lane) * 8);
#pragma unroll
    for (int rt = 0; rt < 4; ++rt)
      acc[rt] = MFMA16(as16(As[(rt * 8 + kk) * 64 + lane]), as16(b), acc[rt]);
  }
  const int col = cb * 64 + w * 16 + cl;
  const float bv = bias[col];
#pragma unroll
  for (int rt = 0; rt < 4; ++rt) {
#pragma unroll
    for (int j = 0; j < 4; ++j) {
      int m = mb * 64 + rt * 16 + q * 4 + j;   // m = b*512 + t
      int t = m & (TT - 1), b = m >> 9;
      Dst[((size_t)t * BB + b) * HH + col] = f2bf(acc[rt][j] + bv);
    }
  }
}

// ============================================================================
// K4: persistent scan, tag-in-data, fragment-major exchange buffers.
//   64 blocks x 256 threads. chain g = blk>>4 (rows 16g..16g+15),
//   col-block c = blk&15 (cols 64c..64c+63). wave w: K-slice [256w,256w+256),
//   owns state for cols c*64+w*16+cl, rows q*4+j (C/D layout).
//   R8: z deferred off the critical path; Vr ct=0 prefetched above the poll.
//   R9.1: poll backoff (see load_validated).
// ============================================================================
__global__ void __launch_bounds__(256, 1) k_scan(
    const unsigned short* __restrict__ XH, const unsigned short* __restrict__ XZ,
    const unsigned short* __restrict__ XR,
    const unsigned short* __restrict__ Whp, const unsigned short* __restrict__ Vzp,
    const unsigned short* __restrict__ Vrp,
    unsigned* __restrict__ hb32all, unsigned* __restrict__ hrb32all,
    float* __restrict__ hfinal) {
  __shared__ f32x4 redA[16 * 64];  // 16 KB
  __shared__ f32x4 redB[16 * 64];  // 16 KB  (z-partials; reduced next step)
  __shared__ f32x4 redC[16 * 64];  // 16 KB

  const int tid = threadIdx.x;
  const int lane = tid & 63, w = tid >> 6;
  const int q = lane >> 4, cl = lane & 15;
  const int blk = blockIdx.x;
  const int g = blk >> 4, c = blk & 15;   // chain, col-block
  const int c4 = c * 4, kw = w * 8;

  unsigned* hb  = hb32all  + (size_t)g * 16 * HH;
  unsigned* hrb = hrb32all + (size_t)g * 16 * HH;

  // resident weight fragments: Wh + Vz (256 VGPRs); Vr streamed per step
  u32x4 wh[4][8], vz[4][8];
#pragma unroll
  for (int ct = 0; ct < 4; ++ct)
#pragma unroll
    for (int k = 0; k < 8; ++k) {
      size_t fi = (((size_t)(c4 + ct) * 32 + kw + k) * 64 + lane) * 8;
      wh[ct][k] = *(const u32x4*)(Whp + fi);
      vz[ct][k] = *(const u32x4*)(Vzp + fi);
    }

  const int hcol = c * 64 + w * 16 + cl;         // owned output column
  const int brow0 = g * 16 + q * 4;              // owned batch rows (+j)

  // consumer read bases (fragment-major): buf + w*4096 + lane*4 dwords
  const unsigned* rpA = hrb + w * 4096 + lane * 4;
  const unsigned* rpB = hb  + w * 4096 + lane * 4;
  // producer store bases: dword idx = (wd*8+kd)*512 + half*256 + laned*4 + jm
  //   wd=C>>8, kd=(C>>5)&7, half=(C>>2)&1, jm=C&3, laned=((C>>3)&3)*16+q*4+j
  const unsigned C = (unsigned)hcol;
  const unsigned sbase = ((C >> 8) * 8 + ((C >> 5) & 7)) * 512 + ((C >> 2) & 1) * 256 +
                         (((C >> 3) & 3) * 16 + q * 4) * 4 + (C & 3);
  unsigned* spA = hb  + sbase;    // row j store at + j*4
  unsigned* spB = hrb + sbase;

  const f32x4 z4 = {0.f, 0.f, 0.f, 0.f};
  f32x4 hreg = z4, zreg = z4;
  unsigned short xz_u[4] = {0, 0, 0, 0};  // carried across steps (deferred z)
  bool dead = false;

  for (int t = 0; t < TT; ++t) {
    // ---------------- phase A: h update ----------------
    unsigned short xh_u[4];
#pragma unroll
    for (int j = 0; j < 4; ++j)
      xh_u[j] = XH[((size_t)t * BB + brow0 + j) * HH + hcol];

    f32x4 acc[4] = {z4, z4, z4, z4};
    if (t > 0) {
      u32x4 a[8];
      load_validated(rpA, (unsigned)t, dead, a);
#pragma unroll
      for (int k = 0; k < 8; ++k) {
        s16x8 av = as16(a[k]);
#pragma unroll
        for (int ct = 0; ct < 4; ++ct)
          acc[ct] = MFMA16(av, as16(wh[ct][k]), acc[ct]);
      }
    }
#pragma unroll
    for (int ct = 0; ct < 4; ++ct) redA[(w * 4 + ct) * 64 + lane] = acc[ct];
    __syncthreads();
    f32x4 S = redA[(0 * 4 + w) * 64 + lane];
    S += redA[(1 * 4 + w) * 64 + lane];
    S += redA[(2 * 4 + w) * 64 + lane];
    S += redA[(3 * 4 + w) * 64 + lane];

    // deferred z from phase B(t-1): redB partials are barrier-covered by the
    // __syncthreads above (all waves wrote redB before reaching it).
    if (t > 0) {
      f32x4 Sz = redB[(0 * 4 + w) * 64 + lane];
      Sz += redB[(1 * 4 + w) * 64 + lane];
      Sz += redB[(2 * 4 + w) * 64 + lane];
      Sz += redB[(3 * 4 + w) * 64 + lane];
#pragma unroll
      for (int j = 0; j < 4; ++j)
        zreg[j] = sigmoid_fast(Sz[j] + bf2f(xz_u[j]));
    }

    float hn[4];
#pragma unroll
    for (int j = 0; j < 4; ++j) {
      float pre = S[j] + bf2f(xh_u[j]);
      float ht = tanh_fast(pre);
      hn[j] = zreg[j] * hreg[j] + (1.f - zreg[j]) * ht;
      hreg[j] = hn[j];
    }
    if (t == TT - 1) break;

    const unsigned tagn = (unsigned)(t + 1);
#pragma unroll
    for (int j = 0; j < 4; ++j)
      st_dw(spA + j * 4, ((unsigned)f2bf(hn[j]) << 16) | tagn);

    // ---------------- phase B: gates (r first, z deferred) ----------------
    unsigned short xr_u[4];
#pragma unroll
    for (int j = 0; j < 4; ++j) {
      xz_u[j] = XZ[((size_t)t * BB + brow0 + j) * HH + hcol];
      xr_u[j] = XR[((size_t)t * BB + brow0 + j) * HH + hcol];
    }
    // prefetch Vr ct=0 above the poll (its "memory" clobber pins loads below)
    u32x4 vr0[8];
#pragma unroll
    for (int k = 0; k < 8; ++k)
      vr0[k] = *(const u32x4*)(Vrp + (((size_t)(c4 + 0) * 32 + kw + k) * 64 + lane) * 8);

    u32x4 b[8];
    load_validated(rpB, tagn, dead, b);

    // r-GEMM only (critical path)
    f32x4 ar[4] = {z4, z4, z4, z4};
#pragma unroll
    for (int k = 0; k < 8; ++k)
      ar[0] = MFMA16(as16(b[k]), as16(vr0[k]), ar[0]);
#pragma unroll
    for (int ct = 1; ct < 4; ++ct) {
      u32x4 vrk[8];
#pragma unroll
      for (int k = 0; k < 8; ++k)
        vrk[k] = *(const u32x4*)(Vrp + (((size_t)(c4 + ct) * 32 + kw + k) * 64 + lane) * 8);
#pragma unroll
      for (int k = 0; k < 8; ++k)
        ar[ct] = MFMA16(as16(b[k]), as16(vrk[k]), ar[ct]);
    }
#pragma unroll
    for (int ct = 0; ct < 4; ++ct) redC[(w * 4 + ct) * 64 + lane] = ar[ct];
    __syncthreads();
    f32x4 Sr = redC[(0 * 4 + w) * 64 + lane];
    Sr += redC[(1 * 4 + w) * 64 + lane];
    Sr += redC[(2 * 4 + w) * 64 + lane];
    Sr += redC[(3 * 4 + w) * 64 + lane];

    float rh[4];
#pragma unroll
    for (int j = 0; j < 4; ++j) {
      float rv = sigmoid_fast(Sr[j] + bf2f(xr_u[j]));
      rh[j] = rv * hreg[j];
    }
#pragma unroll
    for (int j = 0; j < 4; ++j)
      st_dw(spB + j * 4, ((unsigned)f2bf(rh[j]) << 16) | tagn);

    // z-partials (off critical path; reduce deferred to phase A(t+1))
    f32x4 az[4] = {z4, z4, z4, z4};
#pragma unroll
    for (int ct = 0; ct < 4; ++ct)
#pragma unroll
      for (int k = 0; k < 8; ++k)
        az[ct] = MFMA16(as16(b[k]), as16(vz[ct][k]), az[ct]);
#pragma unroll
    for (int ct = 0; ct < 4; ++ct) redB[(w * 4 + ct) * 64 + lane] = az[ct];
    // no barrier here: phase A(t+1)'s __syncthreads covers the redB writes
  }

  // epilogue: final h fp32 (plain stores; visible at kernel boundary)
#pragma unroll
  for (int j = 0; j < 4; ++j)
    hfinal[(size_t)(brow0 + j) * HH + hcol] = hreg[j];
}

// ============================================================================
// K5: out[b][o] = dot(h[b,:], Wo[o,:]) + bo[o]   (fp32)
// ============================================================================
__global__ void __launch_bounds__(256) k_out(const float* __restrict__ hf,
                                             const float* __restrict__ Wo,
                                             const float* __restrict__ bo,
                                             float* __restrict__ out) {
  __shared__ float hs[HH];
  const int b = blockIdx.x, tid = threadIdx.x;
  *(f32x4*)&hs[tid * 4] = *(const f32x4*)(hf + (size_t)b * HH + tid * 4);
  __syncthreads();
  float acc = bo[tid];
  const f32x4* wr = (const f32x4*)(Wo + (size_t)tid * HH);
#pragma unroll 8
  for (int k = 0; k < HH / 4; ++k) {
    f32x4 wv = wr[k];
    f32x4 hv = *(const f32x4*)&hs[k * 4];
    acc += wv[0] * hv[0] + wv[1] * hv[1] + wv[2] * hv[2] + wv[3] * hv[3];
  }
  out[(size_t)b * NOUT + tid] = acc;
}

// ============================================================================
extern "C" void kernel_launch(void* const* d_in, const int* in_sizes, int n_in,
                              void* d_out, int out_size, void* d_ws, size_t ws_size,
                              hipStream_t stream) {
  (void)in_sizes; (void)n_in; (void)out_size; (void)ws_size;
  const float* X  = (const float*)d_in[0];
  const float* Wx = (const float*)d_in[1];
  const float* bx = (const float*)d_in[2];
  const float* Wh = (const float*)d_in[3];
  const float* Uz = (const float*)d_in[4];
  const float* bz = (const float*)d_in[5];
  const float* Vz = (const float*)d_in[6];
  const float* Ur = (const float*)d_in[7];
  const float* br = (const float*)d_in[8];
  const float* Vr = (const float*)d_in[9];
  const float* Wo = (const float*)d_in[10];
  const float* bo = (const float*)d_in[11];

  char* ws = (char*)d_ws;
  unsigned short* XHp = (unsigned short*)(ws + OFF_XH);
  unsigned short* XZp = (unsigned short*)(ws + OFF_XZ);
  unsigned short* XRp = (unsigned short*)(ws + OFF_XR);
  unsigned short* Xb  = (unsigned short*)(ws + OFF_XB);
  unsigned short* Whp = (unsigned short*)(ws + OFF_WHP);
  unsigned short* Vzp = (unsigned short*)(ws + OFF_VZP);
  unsigned short* Vrp = (unsigned short*)(ws + OFF_VRP);
  unsigned short* Wxp = (unsigned short*)(ws + OFF_WXP);
  unsigned short* Uzp = (unsigned short*)(ws + OFF_UZP);
  unsigned short* Urp = (unsigned short*)(ws + OFF_URP);
  unsigned* hbp  = (unsigned*)(ws + OFF_HB);
  unsigned* hrbp = (unsigned*)(ws + OFF_HRB);
  float* hfp = (float*)(ws + OFF_HF);

  k_convert_x<<<8192, 256, 0, stream>>>(X, Xb);
  k_pack_w<<<dim3(512, 6), 256, 0, stream>>>(Wh, Vz, Vr, Wx, Uz, Ur,
                                             Whp, Vzp, Vrp, Wxp, Uzp, Urp);
  k_proj<<<dim3(512, 16, 3), 256, 0, stream>>>(Xb, Wxp, Uzp, Urp, bx, bz, br,
                                               XHp, XZp, XRp);
  k_scan<<<64, 256, 0, stream>>>(XHp, XZp, XRp, Whp, Vzp, Vrp,
                                 hbp, hrbp, hfp);
  k_out<<<64, 256, 0, stream>>>(hfp, Wo, bo, (float*)d_out);
}